// Round 13
// baseline (101.208 us; speedup 1.0000x reference)
//
#include <hip/hip_runtime.h>
#include <hip/hip_bf16.h>
#include <math.h>

#define B_N 4096
#define D_N 512
#define N_NEGS 100
#define N_DOM 8
#define TAU_F 1e-4f
#define EPS_F 1e-6f
#define REGW_F 1e-4f
#define ITEMS_J 101
#define SEXP_LD 102
#define SUPP_NB 528

typedef __attribute__((ext_vector_type(8))) short bf16x8;
typedef __attribute__((ext_vector_type(4))) float f32x4;
typedef __attribute__((ext_vector_type(2))) float f32x2;

// ---- workspace layout (byte offsets). ~13.3 MB used, all plain-store init.
#define PHIF8_B 0u                      // fp8 phi [4096][512]        (2 MB)
#define E2B_B   (2u << 20)              // bf16 e2 [4096][512]        (4 MB)
#define WTB_B   (6u << 20)              // bf16 W^T [512][512]        (0.5 MB)
#define AUGB_B  (WTB_B + (1u << 19))    // bf16 mixup(e1) [4096][512] (4 MB)
#define SEXP_B  (AUGB_B + (4u << 20))   // f32 [4096][102]            (1.7 MB)
#define PDEN_B  (SEXP_B + (2u << 20))   // f32 [32][4096] den partials (512 KB)
#define PNOM_B  (PDEN_B + (1u << 19))   // f32 [32][4096] nom partials (512 KB)
#define STAT_B  (PNOM_B + (1u << 19))   // stats floats
// stat region (float indices) — every slot plain-stored each call, no init
#define S_MSE  0
#define S_B2   1
#define S_WH2  2
#define S_BH2  3
#define S_HIST 8                        // 8 domain counts (as float)
#define S_W2P  16                       // 128 ||W||^2 partials
#define S_FIN  144                      // 64 x {La, Ls} block partials

// ---------------------------------------------------------------------------
__device__ __forceinline__ ushort f2bf(float f) {
    union { __hip_bfloat16 h; ushort u; } v;
    v.h = __float2bfloat16(f);
    return v.u;
}
__device__ __forceinline__ float bf2f(short s) {
    return __uint_as_float(((uint)(ushort)s) << 16);
}

// global->LDS async staging of a 128x64 bf16 tile (linear LDS dest,
// pre-swizzled global source -> reads XOR-swizzle; T2/m201 pattern).
__device__ __forceinline__ void stage_bf16_tile(
        const ushort* __restrict__ g, int row0, int col0, int ldg,
        ushort* lds, int t) {
    int wid = t >> 6, lane = t & 63;
    #pragma unroll
    for (int i = 0; i < 4; ++i) {
        int p = i * 4096 + wid * 1024 + lane * 16;
        int row = p >> 7;
        int colb = (p & 127) ^ ((row & 7) << 4);
        const ushort* src = g + (size_t)(row0 + row) * ldg + col0 + (colb >> 1);
        ushort* dst = lds + (i * 4096 + wid * 1024) / 2;
        __builtin_amdgcn_global_load_lds(
            (const __attribute__((address_space(1))) unsigned int*)src,
            (__attribute__((address_space(3))) unsigned int*)dst, 16, 0, 0);
    }
}
// 64x64 variant (8 KB)
__device__ __forceinline__ void stage_bf16_tile64(
        const ushort* __restrict__ g, int row0, int col0, int ldg,
        ushort* lds, int t) {
    int wid = t >> 6, lane = t & 63;
    #pragma unroll
    for (int i = 0; i < 2; ++i) {
        int p = i * 4096 + wid * 1024 + lane * 16;
        int row = p >> 7;
        int colb = (p & 127) ^ ((row & 7) << 4);
        const ushort* src = g + (size_t)(row0 + row) * ldg + col0 + (colb >> 1);
        ushort* dst = lds + (i * 4096 + wid * 1024) / 2;
        __builtin_amdgcn_global_load_lds(
            (const __attribute__((address_space(1))) unsigned int*)src,
            (__attribute__((address_space(3))) unsigned int*)dst, 16, 0, 0);
    }
}

// ---------------------------------------------------------------------------
__device__ __forceinline__ float block_sum256(float v, float* sred) {
    #pragma unroll
    for (int m = 32; m; m >>= 1) v += __shfl_xor(v, m, 64);
    int lane = threadIdx.x & 63, wid = threadIdx.x >> 6;
    __syncthreads();
    if (lane == 0) sred[wid] = v;
    __syncthreads();
    float s = 0.0f;
    if (threadIdx.x == 0) s = sred[0] + sred[1] + sred[2] + sred[3];
    return s;
}

// ---------------------------------------------------------------------------
// prep: all input-only work, NO atomics (partial-slot writes).
__global__ __launch_bounds__(256) void prep_kernel(
        const float* __restrict__ y_pred, const float* __restrict__ y_target,
        const float* __restrict__ W_e2, const float* __restrict__ b_e2,
        const float* __restrict__ W_head, const float* __restrict__ b_head,
        const float* __restrict__ e2, const float* __restrict__ e1,
        const float* __restrict__ lmbda, const int* __restrict__ mix,
        const int* __restrict__ tag,
        ushort* __restrict__ wtb, ushort* __restrict__ e2b,
        ushort* __restrict__ augb, float* __restrict__ stat) {
    int t = threadIdx.x, x = blockIdx.x, job = blockIdx.y;
    if (job == 2) {
        int i = (x * 256 + t) * 8;
        f32x4 v0 = *(const f32x4*)(e2 + i);
        f32x4 v1 = *(const f32x4*)(e2 + i + 4);
        bf16x8 o;
        o[0] = (short)f2bf(v0.x); o[1] = (short)f2bf(v0.y);
        o[2] = (short)f2bf(v0.z); o[3] = (short)f2bf(v0.w);
        o[4] = (short)f2bf(v1.x); o[5] = (short)f2bf(v1.y);
        o[6] = (short)f2bf(v1.z); o[7] = (short)f2bf(v1.w);
        *(bf16x8*)(e2b + i) = o;
        return;
    }
    if (job == 3) {
        int i = (x * 256 + t) * 8;
        int row = i >> 9, col = i & 511;
        float lam = lmbda[row], oml = 1.0f - lam;
        const float* a = e1 + (size_t)row * D_N + col;
        const float* c = e1 + (size_t)mix[row] * D_N + col;
        f32x4 a0 = *(const f32x4*)a, a1 = *(const f32x4*)(a + 4);
        f32x4 c0 = *(const f32x4*)c, c1 = *(const f32x4*)(c + 4);
        bf16x8 o;
        o[0] = (short)f2bf(lam * a0.x + oml * c0.x);
        o[1] = (short)f2bf(lam * a0.y + oml * c0.y);
        o[2] = (short)f2bf(lam * a0.z + oml * c0.z);
        o[3] = (short)f2bf(lam * a0.w + oml * c0.w);
        o[4] = (short)f2bf(lam * a1.x + oml * c1.x);
        o[5] = (short)f2bf(lam * a1.y + oml * c1.y);
        o[6] = (short)f2bf(lam * a1.z + oml * c1.z);
        o[7] = (short)f2bf(lam * a1.w + oml * c1.w);
        *(bf16x8*)(augb + i) = o;
        return;
    }
    if (job == 1) {
        if (x >= 64) return;
        __shared__ float tile[64][65];
        int k0 = (x >> 3) * 64, n0 = (x & 7) * 64;
        int r = t >> 4, c = (t & 15) * 4;
        #pragma unroll
        for (int i = 0; i < 4; ++i) {
            f32x4 v = *(const f32x4*)(W_e2 + (size_t)(k0 + r + i * 16) * D_N + n0 + c);
            tile[r + i * 16][c]     = v.x;
            tile[r + i * 16][c + 1] = v.y;
            tile[r + i * 16][c + 2] = v.z;
            tile[r + i * 16][c + 3] = v.w;
        }
        __syncthreads();
        int nl = t >> 2, kq = (t & 3) * 16;
        bf16x8 o0, o1;
        #pragma unroll
        for (int q = 0; q < 8; ++q) o0[q] = (short)f2bf(tile[kq + q][nl]);
        #pragma unroll
        for (int q = 0; q < 8; ++q) o1[q] = (short)f2bf(tile[kq + 8 + q][nl]);
        ushort* dst = wtb + (size_t)(n0 + nl) * D_N + k0 + kq;
        *(bf16x8*)dst = o0;
        *(bf16x8*)(dst + 8) = o1;
        return;
    }
    // job == 0
    __shared__ float sred[4];
    if (x < 128) {
        float s = 0.0f;
        for (int i = x * 256 + t; i < D_N * D_N; i += 128 * 256) {
            float w = W_e2[i]; s += w * w;
        }
        s = block_sum256(s, sred);
        if (t == 0) stat[S_W2P + x] = s;
    } else if (x == 128) {
        float s = 0.0f;
        for (int i = t; i < B_N; i += 256) {
            float d = y_pred[i] - y_target[i]; s += d * d;
        }
        s = block_sum256(s, sred);
        if (t == 0) stat[S_MSE] = s;
    } else if (x == 129) {
        float v1 = b_e2[t], v2 = b_e2[t + 256];
        float s = block_sum256(v1 * v1 + v2 * v2, sred);
        if (t == 0) stat[S_B2] = s;
        v1 = W_head[t]; v2 = W_head[t + 256];
        s = block_sum256(v1 * v1 + v2 * v2, sred);
        if (t == 0) {
            stat[S_WH2] = s;
            stat[S_BH2] = b_head[0] * b_head[0];
        }
    } else if (x == 130) {
        __shared__ int h[N_DOM];
        if (t < N_DOM) h[t] = 0;
        __syncthreads();
        for (int i = t; i < B_N; i += 256) atomicAdd(&h[tag[i]], 1);
        __syncthreads();
        if (t < N_DOM) stat[S_HIST + t] = (float)h[t];
    }
}

// ---------------------------------------------------------------------------
// phi = augb @ wtb^T + b -> fp8.  64x128 tile (256 blocks, 24 KB LDS).
__global__ __launch_bounds__(256) void phi_kernel(
        const ushort* __restrict__ augb, const ushort* __restrict__ wtb,
        const float* __restrict__ bvec, unsigned char* __restrict__ phif8) {
    __shared__ ushort As[64 * 64];
    __shared__ ushort Bs[128 * 64];
    int rb = blockIdx.y * 64, cb = blockIdx.x * 128;
    int t = threadIdx.x;
    int lane = t & 63, wid = t >> 6;
    int l15 = lane & 15, g = lane >> 4, x7 = l15 & 7;
    int wr = wid >> 1, wc = wid & 1;

    f32x4 acc[2][4] = {};
    for (int kk = 0; kk < D_N; kk += 64) {
        __syncthreads();
        stage_bf16_tile64(augb, rb, kk, D_N, As, t);
        stage_bf16_tile  (wtb,  cb, kk, D_N, Bs, t);
        __syncthreads();
        bf16x8 a[2][2], b[4][2];
        #pragma unroll
        for (int mi = 0; mi < 2; ++mi)
            #pragma unroll
            for (int ks = 0; ks < 2; ++ks) {
                int ar = wr * 32 + mi * 16 + l15;
                a[mi][ks] = *(const bf16x8*)((const char*)As +
                    ar * 128 + (((ks << 2) | g) ^ x7) * 16);
            }
        #pragma unroll
        for (int ni = 0; ni < 4; ++ni)
            #pragma unroll
            for (int ks = 0; ks < 2; ++ks) {
                int br = wc * 64 + ni * 16 + l15;
                b[ni][ks] = *(const bf16x8*)((const char*)Bs +
                    br * 128 + (((ks << 2) | g) ^ x7) * 16);
            }
        #pragma unroll
        for (int mi = 0; mi < 2; ++mi)
            #pragma unroll
            for (int ni = 0; ni < 4; ++ni)
                #pragma unroll
                for (int ks = 0; ks < 2; ++ks)
                    acc[mi][ni] = __builtin_amdgcn_mfma_f32_16x16x32_bf16(
                        a[mi][ks], b[ni][ks], acc[mi][ni], 0, 0, 0);
    }
    float bb[4];
    #pragma unroll
    for (int ni = 0; ni < 4; ++ni) bb[ni] = bvec[cb + wc * 64 + ni * 16 + l15];
    #pragma unroll
    for (int mi = 0; mi < 2; ++mi)
        #pragma unroll
        for (int r = 0; r < 4; ++r) {
            int row = rb + wr * 32 + mi * 16 + g * 4 + r;
            #pragma unroll
            for (int ni = 0; ni < 4; ++ni) {
                int col = cb + wc * 64 + ni * 16 + l15;
                float v = acc[mi][ni][r] + bb[ni];
                phif8[(size_t)row * D_N + col] = (unsigned char)
                    (__builtin_amdgcn_cvt_pk_fp8_f32(v, v, 0, false) & 0xff);
            }
        }
}

// ---------------------------------------------------------------------------
// fused: blocks [0,528) = supp triangular Gram tiles (MFMA-bound, plain-store
// partial slots); blocks [528,13456) = aug gather groups (VMEM-latency-bound,
// plain stores to sexp). NO global atomics anywhere (round-10 failure cause
// removed). Complementary pipe usage -> co-scheduled overlap (m114).
__global__ __launch_bounds__(256) void fused_kernel(
        const ushort* __restrict__ e2b, const int* __restrict__ tag,
        const unsigned char* __restrict__ phif8, const int* __restrict__ neg_idx,
        float* __restrict__ pden, float* __restrict__ pnom,
        float* __restrict__ sexp) {
    __shared__ ushort As[128 * 64];
    __shared__ ushort Bs[128 * 64];
    __shared__ int rt_s[128], ct_s[128];
    int t = threadIdx.x;

    if (blockIdx.x >= SUPP_NB) {
        // ---------------- aug gather part (plain stores only) ----------------
        int gi = (blockIdx.x - SUPP_NB) * 32 + (t >> 3);
        int sub = t & 7;
        int j = gi / ITEMS_J;
        int idx = gi - j * ITEMS_J;
        int tgt = (idx == 0) ? j : neg_idx[(size_t)j * N_NEGS + idx - 1];
        const ushort* e        = e2b   + (size_t)j   * D_N + sub * 8;
        const unsigned char* p = phif8 + (size_t)tgt * D_N + sub * 8;
        uint2 pv[8]; bf16x8 ev[8];
        #pragma unroll
        for (int k = 0; k < 8; ++k) {
            pv[k] = *(const uint2*)(p + k * 64);
            ev[k] = *(const bf16x8*)(e + k * 64);
        }
        float s0 = 0.f, s1 = 0.f;
        #pragma unroll
        for (int k = 0; k < 8; ++k) {
            f32x2 a0 = __builtin_amdgcn_cvt_pk_f32_fp8((int)pv[k].x, false);
            f32x2 a1 = __builtin_amdgcn_cvt_pk_f32_fp8((int)pv[k].x, true);
            f32x2 a2 = __builtin_amdgcn_cvt_pk_f32_fp8((int)pv[k].y, false);
            f32x2 a3 = __builtin_amdgcn_cvt_pk_f32_fp8((int)pv[k].y, true);
            s0 += bf2f(ev[k][0]) * a0.x + bf2f(ev[k][1]) * a0.y
                + bf2f(ev[k][2]) * a1.x + bf2f(ev[k][3]) * a1.y;
            s1 += bf2f(ev[k][4]) * a2.x + bf2f(ev[k][5]) * a2.y
                + bf2f(ev[k][6]) * a3.x + bf2f(ev[k][7]) * a3.y;
        }
        float s = s0 + s1;
        s += __shfl_xor(s, 1);
        s += __shfl_xor(s, 2);
        s += __shfl_xor(s, 4);
        if (sub == 0) sexp[(size_t)j * SEXP_LD + idx] = __expf(TAU_F * s);
        return;
    }

    // ---------------- supp triangular Gram part ----------------
    int tid = blockIdx.x;                      // 0..527
    int sw = (tid & 7) * 66 + (tid >> 3);      // XCD swizzle (528 = 8*66)
    int by = (int)((sqrtf(8.0f * (float)sw + 1.0f) - 1.0f) * 0.5f);
    while ((by + 1) * (by + 2) / 2 <= sw) ++by;
    while (by * (by + 1) / 2 > sw) --by;
    int bx = sw - by * (by + 1) / 2;           // bx <= by
    bool diag = (bx == by);
    int rb = by * 128, cb = bx * 128;
    if (t < 128) rt_s[t] = tag[rb + t];
    else         ct_s[t - 128] = tag[cb + t - 128];

    int lane = t & 63, wid = t >> 6;
    int l15 = lane & 15, g = lane >> 4, x7 = l15 & 7;
    int wr = wid >> 1, wc = wid & 1;

    f32x4 acc[4][4] = {};
    for (int kk = 0; kk < D_N; kk += 64) {
        __syncthreads();
        stage_bf16_tile(e2b, rb, kk, D_N, As, t);
        stage_bf16_tile(e2b, cb, kk, D_N, Bs, t);
        __syncthreads();
        bf16x8 a[4][2], b[4][2];
        #pragma unroll
        for (int mi = 0; mi < 4; ++mi)
            #pragma unroll
            for (int ks = 0; ks < 2; ++ks) {
                int ar = wr * 64 + mi * 16 + l15;
                a[mi][ks] = *(const bf16x8*)((const char*)As +
                    ar * 128 + (((ks << 2) | g) ^ x7) * 16);
                int br = wc * 64 + mi * 16 + l15;
                b[mi][ks] = *(const bf16x8*)((const char*)Bs +
                    br * 128 + (((ks << 2) | g) ^ x7) * 16);
            }
        #pragma unroll
        for (int mi = 0; mi < 4; ++mi)
            #pragma unroll
            for (int ni = 0; ni < 4; ++ni)
                #pragma unroll
                for (int ks = 0; ks < 2; ++ks)
                    acc[mi][ni] = __builtin_amdgcn_mfma_f32_16x16x32_bf16(
                        a[mi][ks], b[ni][ks], acc[mi][ni], 0, 0, 0);
    }
    int ct[4];
    #pragma unroll
    for (int ni = 0; ni < 4; ++ni) ct[ni] = ct_s[wc * 64 + ni * 16 + l15];
    float cd[4] = {}, cn[4] = {};
    #pragma unroll
    for (int mi = 0; mi < 4; ++mi) {
        #pragma unroll
        for (int r = 0; r < 4; ++r) {
            int row = wr * 64 + mi * 16 + g * 4 + r;
            int rt = rt_s[row];
            float d = 0.f, n = 0.f;
            #pragma unroll
            for (int ni = 0; ni < 4; ++ni) {
                float v = __expf(TAU_F * acc[mi][ni][r]);
                float nv = (ct[ni] != rt) ? v : 0.f;
                d += v; n += nv;
                cd[ni] += v; cn[ni] += nv;
            }
            #pragma unroll
            for (int mm = 1; mm < 16; mm <<= 1) {
                d += __shfl_xor(d, mm);
                n += __shfl_xor(n, mm);
            }
            if (l15 == 0) {
                pden[bx * B_N + rb + row] = d;   // slot bx, plain store
                pnom[bx * B_N + rb + row] = n;
            }
        }
    }
    if (!diag) {
        #pragma unroll
        for (int ni = 0; ni < 4; ++ni) {
            float d = cd[ni], n = cn[ni];
            d += __shfl_xor(d, 16); d += __shfl_xor(d, 32);
            n += __shfl_xor(n, 16); n += __shfl_xor(n, 32);
            if (g == 0) {
                int col = wc * 64 + ni * 16 + l15;
                pden[by * B_N + cb + col] = d;   // slot by, plain store
                pnom[by * B_N + cb + col] = n;
            }
        }
    }
}

// ---------------------------------------------------------------------------
// final1: 64 blocks; per j: reduce sexp row -> L_a, reduce 32 den/nom
// partial slots -> L_s; write per-block {La,Ls} partials (plain stores).
__global__ __launch_bounds__(256) void final1_kernel(
        const float* __restrict__ sexp, const float* __restrict__ pden,
        const float* __restrict__ pnom, const int* __restrict__ tag,
        float* __restrict__ stat) {
    __shared__ float wla[4], wls[4];
    int lane = threadIdx.x & 63, w = threadIdx.x >> 6;
    int j0 = blockIdx.x * 64;
    float la = 0.f, ls = 0.f;
    for (int jj = w; jj < 64; jj += 4) {
        int j = j0 + jj;
        float v0 = sexp[(size_t)j * SEXP_LD + lane];
        float v1 = (lane + 64 < ITEMS_J) ? sexp[(size_t)j * SEXP_LD + lane + 64] : 0.f;
        float pos = __shfl(v0, 0);
        float ns = ((lane >= 1) ? v0 : 0.f) + v1;
        float d = (lane < 32) ? pden[lane * B_N + j] : 0.f;
        float n = (lane < 32) ? pnom[lane * B_N + j] : 0.f;
        #pragma unroll
        for (int mm = 32; mm; mm >>= 1) {
            ns += __shfl_xor(ns, mm);
            d  += __shfl_xor(d, mm);
            n  += __shfl_xor(n, mm);
        }
        if (lane == 0) {
            float La = logf(pos / (EPS_F + pos + ns));
            if (La == La) la += La;
            float Ls = logf(n / (d + EPS_F));
            bool valid = (stat[S_HIST + tag[j]] < (float)B_N) && (Ls == Ls);
            if (valid) ls += Ls;
        }
    }
    if (lane == 0) { wla[w] = la; wls[w] = ls; }
    __syncthreads();
    if (threadIdx.x == 0) {
        stat[S_FIN + blockIdx.x * 2]     = wla[0] + wla[1] + wla[2] + wla[3];
        stat[S_FIN + blockIdx.x * 2 + 1] = wls[0] + wls[1] + wls[2] + wls[3];
    }
}

// ---------------------------------------------------------------------------
__global__ __launch_bounds__(256) void final2_kernel(
        const float* __restrict__ stat, float* __restrict__ out) {
    __shared__ float sred[4];
    int t = threadIdx.x;
    float w2 = block_sum256(t < 128 ? stat[S_W2P + t] : 0.f, sred);
    float la = block_sum256(t < 64 ? stat[S_FIN + 2 * t] : 0.f, sred);
    float ls = block_sum256(t < 64 ? stat[S_FIN + 2 * t + 1] : 0.f, sred);
    if (t == 0) {
        out[0] = stat[S_MSE] / (float)B_N;
        out[1] = REGW_F * (sqrtf(w2) + sqrtf(stat[S_B2]) +
                           sqrtf(stat[S_WH2]) + sqrtf(stat[S_BH2]));
        out[2] = -la / (float)B_N;
        out[3] = -ls / (float)B_N;
    }
}

// ---------------------------------------------------------------------------
extern "C" void kernel_launch(void* const* d_in, const int* in_sizes, int n_in,
                              void* d_out, int out_size, void* d_ws, size_t ws_size,
                              hipStream_t stream) {
    const float* e1       = (const float*)d_in[0];
    const float* e2       = (const float*)d_in[1];
    const float* y_pred   = (const float*)d_in[2];
    const float* y_target = (const float*)d_in[3];
    const float* W_e2     = (const float*)d_in[4];
    const float* b_e2     = (const float*)d_in[5];
    const float* W_head   = (const float*)d_in[6];
    const float* b_head   = (const float*)d_in[7];
    const float* lmbda    = (const float*)d_in[8];
    const int*   mix_idx  = (const int*)d_in[9];
    const int*   neg_idx  = (const int*)d_in[10];
    const int*   dtag     = (const int*)d_in[11];
    char* base = (char*)d_ws;
    float* out = (float*)d_out;
    unsigned char* phif8 = (unsigned char*)(base + PHIF8_B);
    ushort* e2b  = (ushort*)(base + E2B_B);
    ushort* wtb  = (ushort*)(base + WTB_B);
    ushort* augb = (ushort*)(base + AUGB_B);
    float*  sexp = (float*)(base + SEXP_B);
    float*  pden = (float*)(base + PDEN_B);
    float*  pnom = (float*)(base + PNOM_B);
    float*  stat = (float*)(base + STAT_B);

    prep_kernel<<<dim3(1024, 4), dim3(256), 0, stream>>>(
        y_pred, y_target, W_e2, b_e2, W_head, b_head, e2, e1, lmbda, mix_idx,
        dtag, wtb, e2b, augb, stat);
    phi_kernel<<<dim3(D_N / 128, B_N / 64), dim3(256), 0, stream>>>(
        augb, wtb, b_e2, phif8);
    fused_kernel<<<dim3(SUPP_NB + B_N * ITEMS_J / 32), dim3(256), 0, stream>>>(
        e2b, dtag, phif8, neg_idx, pden, pnom, sexp);
    final1_kernel<<<dim3(64), dim3(256), 0, stream>>>(
        sexp, pden, pnom, dtag, stat);
    final2_kernel<<<dim3(1), dim3(256), 0, stream>>>(stat, out);
}

// Round 14
// 87.971 us; speedup vs baseline: 1.1505x; 1.1505x over previous
//
#include <hip/hip_runtime.h>
#include <hip/hip_bf16.h>
#include <math.h>

#define B_N 4096
#define D_N 512
#define N_NEGS 100
#define N_DOM 8
#define TAU_F 1e-4f
#define EPS_F 1e-6f
#define REGW_F 1e-4f
#define ITEMS_J 101
#define SEXP_LD 102

typedef __attribute__((ext_vector_type(8))) short bf16x8;
typedef __attribute__((ext_vector_type(4))) float f32x4;
typedef __attribute__((ext_vector_type(2))) float f32x2;

// ---- workspace layout (byte offsets). ~15.5 MB used, all plain-store init.
#define PHIF8_B 0u                      // fp8 phi [4096][512]        (2 MB)
#define E2B_B   (2u << 20)              // bf16 e2 [4096][512]        (4 MB)
#define WTB_B   (6u << 20)              // bf16 W^T [512][512]        (0.5 MB)
#define AUGB_B  (WTB_B + (1u << 19))    // bf16 mixup(e1) [4096][512] (4 MB)
#define SEXP_B  (AUGB_B + (4u << 20))   // f32 [4096][102]            (1.7 MB)
#define PDEN_B  (SEXP_B + (2u << 20))   // f32 [32][4096] den partials (512 KB)
#define PNOM_B  (PDEN_B + (1u << 19))   // f32 [32][4096] nom partials (512 KB)
#define E2F8_B  (PNOM_B + (1u << 19))   // fp8 e2 [4096][512]         (2 MB)
#define STAT_B  (E2F8_B + (2u << 20))   // stats floats
// stat region (float indices) — every slot plain-stored each call, no init
#define S_MSE  0
#define S_B2   1
#define S_WH2  2
#define S_BH2  3
#define S_HIST 8                        // 8 domain counts (as float)
#define S_W2P  16                       // 128 ||W||^2 partials
#define S_FIN  144                      // 64 x {La, Ls} block partials

// ---------------------------------------------------------------------------
__device__ __forceinline__ ushort f2bf(float f) {
    union { __hip_bfloat16 h; ushort u; } v;
    v.h = __float2bfloat16(f);
    return v.u;
}
__device__ __forceinline__ float bf2f(short s) {
    return __uint_as_float(((uint)(ushort)s) << 16);
}

// global->LDS async staging of a 128x64 bf16 tile (linear LDS dest,
// pre-swizzled global source -> reads XOR-swizzle; T2/m201 pattern).
__device__ __forceinline__ void stage_bf16_tile(
        const ushort* __restrict__ g, int row0, int col0, int ldg,
        ushort* lds, int t) {
    int wid = t >> 6, lane = t & 63;
    #pragma unroll
    for (int i = 0; i < 4; ++i) {
        int p = i * 4096 + wid * 1024 + lane * 16;
        int row = p >> 7;
        int colb = (p & 127) ^ ((row & 7) << 4);
        const ushort* src = g + (size_t)(row0 + row) * ldg + col0 + (colb >> 1);
        ushort* dst = lds + (i * 4096 + wid * 1024) / 2;
        __builtin_amdgcn_global_load_lds(
            (const __attribute__((address_space(1))) unsigned int*)src,
            (__attribute__((address_space(3))) unsigned int*)dst, 16, 0, 0);
    }
}
// 64x64 bf16 variant (8 KB)
__device__ __forceinline__ void stage_bf16_tile64(
        const ushort* __restrict__ g, int row0, int col0, int ldg,
        ushort* lds, int t) {
    int wid = t >> 6, lane = t & 63;
    #pragma unroll
    for (int i = 0; i < 2; ++i) {
        int p = i * 4096 + wid * 1024 + lane * 16;
        int row = p >> 7;
        int colb = (p & 127) ^ ((row & 7) << 4);
        const ushort* src = g + (size_t)(row0 + row) * ldg + col0 + (colb >> 1);
        ushort* dst = lds + (i * 4096 + wid * 1024) / 2;
        __builtin_amdgcn_global_load_lds(
            (const __attribute__((address_space(1))) unsigned int*)src,
            (__attribute__((address_space(3))) unsigned int*)dst, 16, 0, 0);
    }
}
// 128x128 fp8 tile (16 KB): rows are 128 B -> identical byte arithmetic.
__device__ __forceinline__ void stage_fp8_tile(
        const unsigned char* __restrict__ g, int row0, int col0, int ldg,
        unsigned char* lds, int t) {
    int wid = t >> 6, lane = t & 63;
    #pragma unroll
    for (int i = 0; i < 4; ++i) {
        int p = i * 4096 + wid * 1024 + lane * 16;
        int row = p >> 7;
        int colb = (p & 127) ^ ((row & 7) << 4);
        const unsigned char* src = g + (size_t)(row0 + row) * ldg + col0 + colb;
        unsigned char* dst = lds + i * 4096 + wid * 1024;
        __builtin_amdgcn_global_load_lds(
            (const __attribute__((address_space(1))) unsigned int*)src,
            (__attribute__((address_space(3))) unsigned int*)dst, 16, 0, 0);
    }
}

// ---------------------------------------------------------------------------
__device__ __forceinline__ float block_sum256(float v, float* sred) {
    #pragma unroll
    for (int m = 32; m; m >>= 1) v += __shfl_xor(v, m, 64);
    int lane = threadIdx.x & 63, wid = threadIdx.x >> 6;
    __syncthreads();
    if (lane == 0) sred[wid] = v;
    __syncthreads();
    float s = 0.0f;
    if (threadIdx.x == 0) s = sred[0] + sred[1] + sred[2] + sred[3];
    return s;
}

// ---------------------------------------------------------------------------
// prep: all input-only work, NO atomics (partial-slot writes).
//   y==0: x<128 W2 partials; x==128 mse; x==129 small norms; x==130 histogram
//   y==1: x<64  wtb transpose tiles
//   y==2: e2 -> bf16
//   y==3: mixup(e1) -> bf16 augb
//   y==4: e2 -> fp8 (supp operand)
__global__ __launch_bounds__(256) void prep_kernel(
        const float* __restrict__ y_pred, const float* __restrict__ y_target,
        const float* __restrict__ W_e2, const float* __restrict__ b_e2,
        const float* __restrict__ W_head, const float* __restrict__ b_head,
        const float* __restrict__ e2, const float* __restrict__ e1,
        const float* __restrict__ lmbda, const int* __restrict__ mix,
        const int* __restrict__ tag,
        ushort* __restrict__ wtb, ushort* __restrict__ e2b,
        ushort* __restrict__ augb, unsigned char* __restrict__ e2f8,
        float* __restrict__ stat) {
    int t = threadIdx.x, x = blockIdx.x, job = blockIdx.y;
    if (job == 2) {
        int i = (x * 256 + t) * 8;
        f32x4 v0 = *(const f32x4*)(e2 + i);
        f32x4 v1 = *(const f32x4*)(e2 + i + 4);
        bf16x8 o;
        o[0] = (short)f2bf(v0.x); o[1] = (short)f2bf(v0.y);
        o[2] = (short)f2bf(v0.z); o[3] = (short)f2bf(v0.w);
        o[4] = (short)f2bf(v1.x); o[5] = (short)f2bf(v1.y);
        o[6] = (short)f2bf(v1.z); o[7] = (short)f2bf(v1.w);
        *(bf16x8*)(e2b + i) = o;
        return;
    }
    if (job == 4) {                      // e2 -> fp8 e4m3
        int i = (x * 256 + t) * 8;
        f32x4 v0 = *(const f32x4*)(e2 + i);
        f32x4 v1 = *(const f32x4*)(e2 + i + 4);
        int w0 = 0, w1 = 0;
        w0 = __builtin_amdgcn_cvt_pk_fp8_f32(v0.x, v0.y, w0, false);
        w0 = __builtin_amdgcn_cvt_pk_fp8_f32(v0.z, v0.w, w0, true);
        w1 = __builtin_amdgcn_cvt_pk_fp8_f32(v1.x, v1.y, w1, false);
        w1 = __builtin_amdgcn_cvt_pk_fp8_f32(v1.z, v1.w, w1, true);
        *(int2*)(e2f8 + i) = make_int2(w0, w1);
        return;
    }
    if (job == 3) {
        int i = (x * 256 + t) * 8;
        int row = i >> 9, col = i & 511;
        float lam = lmbda[row], oml = 1.0f - lam;
        const float* a = e1 + (size_t)row * D_N + col;
        const float* c = e1 + (size_t)mix[row] * D_N + col;
        f32x4 a0 = *(const f32x4*)a, a1 = *(const f32x4*)(a + 4);
        f32x4 c0 = *(const f32x4*)c, c1 = *(const f32x4*)(c + 4);
        bf16x8 o;
        o[0] = (short)f2bf(lam * a0.x + oml * c0.x);
        o[1] = (short)f2bf(lam * a0.y + oml * c0.y);
        o[2] = (short)f2bf(lam * a0.z + oml * c0.z);
        o[3] = (short)f2bf(lam * a0.w + oml * c0.w);
        o[4] = (short)f2bf(lam * a1.x + oml * c1.x);
        o[5] = (short)f2bf(lam * a1.y + oml * c1.y);
        o[6] = (short)f2bf(lam * a1.z + oml * c1.z);
        o[7] = (short)f2bf(lam * a1.w + oml * c1.w);
        *(bf16x8*)(augb + i) = o;
        return;
    }
    if (job == 1) {
        if (x >= 64) return;
        __shared__ float tile[64][65];
        int k0 = (x >> 3) * 64, n0 = (x & 7) * 64;
        int r = t >> 4, c = (t & 15) * 4;
        #pragma unroll
        for (int i = 0; i < 4; ++i) {
            f32x4 v = *(const f32x4*)(W_e2 + (size_t)(k0 + r + i * 16) * D_N + n0 + c);
            tile[r + i * 16][c]     = v.x;
            tile[r + i * 16][c + 1] = v.y;
            tile[r + i * 16][c + 2] = v.z;
            tile[r + i * 16][c + 3] = v.w;
        }
        __syncthreads();
        int nl = t >> 2, kq = (t & 3) * 16;
        bf16x8 o0, o1;
        #pragma unroll
        for (int q = 0; q < 8; ++q) o0[q] = (short)f2bf(tile[kq + q][nl]);
        #pragma unroll
        for (int q = 0; q < 8; ++q) o1[q] = (short)f2bf(tile[kq + 8 + q][nl]);
        ushort* dst = wtb + (size_t)(n0 + nl) * D_N + k0 + kq;
        *(bf16x8*)dst = o0;
        *(bf16x8*)(dst + 8) = o1;
        return;
    }
    // job == 0
    __shared__ float sred[4];
    if (x < 128) {
        float s = 0.0f;
        for (int i = x * 256 + t; i < D_N * D_N; i += 128 * 256) {
            float w = W_e2[i]; s += w * w;
        }
        s = block_sum256(s, sred);
        if (t == 0) stat[S_W2P + x] = s;
    } else if (x == 128) {
        float s = 0.0f;
        for (int i = t; i < B_N; i += 256) {
            float d = y_pred[i] - y_target[i]; s += d * d;
        }
        s = block_sum256(s, sred);
        if (t == 0) stat[S_MSE] = s;
    } else if (x == 129) {
        float v1 = b_e2[t], v2 = b_e2[t + 256];
        float s = block_sum256(v1 * v1 + v2 * v2, sred);
        if (t == 0) stat[S_B2] = s;
        v1 = W_head[t]; v2 = W_head[t + 256];
        s = block_sum256(v1 * v1 + v2 * v2, sred);
        if (t == 0) {
            stat[S_WH2] = s;
            stat[S_BH2] = b_head[0] * b_head[0];
        }
    } else if (x == 130) {
        __shared__ int h[N_DOM];
        if (t < N_DOM) h[t] = 0;
        __syncthreads();
        for (int i = t; i < B_N; i += 256) atomicAdd(&h[tag[i]], 1);
        __syncthreads();
        if (t < N_DOM) stat[S_HIST + t] = (float)h[t];
    }
}

// ---------------------------------------------------------------------------
// phi = augb @ wtb^T + b -> fp8.  64x128 tile (256 blocks, 24 KB LDS).
__global__ __launch_bounds__(256) void phi_kernel(
        const ushort* __restrict__ augb, const ushort* __restrict__ wtb,
        const float* __restrict__ bvec, unsigned char* __restrict__ phif8) {
    __shared__ ushort As[64 * 64];
    __shared__ ushort Bs[128 * 64];
    int rb = blockIdx.y * 64, cb = blockIdx.x * 128;
    int t = threadIdx.x;
    int lane = t & 63, wid = t >> 6;
    int l15 = lane & 15, g = lane >> 4, x7 = l15 & 7;
    int wr = wid >> 1, wc = wid & 1;

    f32x4 acc[2][4] = {};
    for (int kk = 0; kk < D_N; kk += 64) {
        __syncthreads();
        stage_bf16_tile64(augb, rb, kk, D_N, As, t);
        stage_bf16_tile  (wtb,  cb, kk, D_N, Bs, t);
        __syncthreads();
        bf16x8 a[2][2], b[4][2];
        #pragma unroll
        for (int mi = 0; mi < 2; ++mi)
            #pragma unroll
            for (int ks = 0; ks < 2; ++ks) {
                int ar = wr * 32 + mi * 16 + l15;
                a[mi][ks] = *(const bf16x8*)((const char*)As +
                    ar * 128 + (((ks << 2) | g) ^ x7) * 16);
            }
        #pragma unroll
        for (int ni = 0; ni < 4; ++ni)
            #pragma unroll
            for (int ks = 0; ks < 2; ++ks) {
                int br = wc * 64 + ni * 16 + l15;
                b[ni][ks] = *(const bf16x8*)((const char*)Bs +
                    br * 128 + (((ks << 2) | g) ^ x7) * 16);
            }
        #pragma unroll
        for (int mi = 0; mi < 2; ++mi)
            #pragma unroll
            for (int ni = 0; ni < 4; ++ni)
                #pragma unroll
                for (int ks = 0; ks < 2; ++ks)
                    acc[mi][ni] = __builtin_amdgcn_mfma_f32_16x16x32_bf16(
                        a[mi][ks], b[ni][ks], acc[mi][ni], 0, 0, 0);
    }
    float bb[4];
    #pragma unroll
    for (int ni = 0; ni < 4; ++ni) bb[ni] = bvec[cb + wc * 64 + ni * 16 + l15];
    #pragma unroll
    for (int mi = 0; mi < 2; ++mi)
        #pragma unroll
        for (int r = 0; r < 4; ++r) {
            int row = rb + wr * 32 + mi * 16 + g * 4 + r;
            #pragma unroll
            for (int ni = 0; ni < 4; ++ni) {
                int col = cb + wc * 64 + ni * 16 + l15;
                float v = acc[mi][ni][r] + bb[ni];
                phif8[(size_t)row * D_N + col] = (unsigned char)
                    (__builtin_amdgcn_cvt_pk_fp8_f32(v, v, 0, false) & 0xff);
            }
        }
}

// ---------------------------------------------------------------------------
// supp: triangular Gram in fp8 e4m3, BK=128 (4 K-steps, half the barriers of
// the bf16 BK=64 form at the same 32 KB LDS). Plain-store partial slots.
// Fragment: 8 fp8/lane, k = 32*ks + 8*(lane>>4), same swizzle byte math.
__global__ __launch_bounds__(256) void supp_kernel(
        const unsigned char* __restrict__ e2f8, const int* __restrict__ tag,
        float* __restrict__ pden, float* __restrict__ pnom) {
    __shared__ unsigned char As8[128 * 128];
    __shared__ unsigned char Bs8[128 * 128];
    __shared__ int rt_s[128], ct_s[128];

    int tid = blockIdx.x;                      // 0..527
    int sw = (tid & 7) * 66 + (tid >> 3);      // XCD swizzle (528 = 8*66)
    int by = (int)((sqrtf(8.0f * (float)sw + 1.0f) - 1.0f) * 0.5f);
    while ((by + 1) * (by + 2) / 2 <= sw) ++by;
    while (by * (by + 1) / 2 > sw) --by;
    int bx = sw - by * (by + 1) / 2;           // bx <= by
    bool diag = (bx == by);
    int rb = by * 128, cb = bx * 128;
    int t = threadIdx.x;
    if (t < 128) rt_s[t] = tag[rb + t];
    else         ct_s[t - 128] = tag[cb + t - 128];

    int lane = t & 63, wid = t >> 6;
    int l15 = lane & 15, g = lane >> 4, x7 = l15 & 7;
    int wr = wid >> 1, wc = wid & 1;

    f32x4 acc[4][4] = {};
    for (int kk = 0; kk < D_N; kk += 128) {
        __syncthreads();
        stage_fp8_tile(e2f8, rb, kk, D_N, As8, t);
        stage_fp8_tile(e2f8, cb, kk, D_N, Bs8, t);
        __syncthreads();
        long a[4][4], b[4][4];
        #pragma unroll
        for (int mi = 0; mi < 4; ++mi) {
            int ar = wr * 64 + mi * 16 + l15;
            int br = wc * 64 + mi * 16 + l15;
            #pragma unroll
            for (int ks = 0; ks < 4; ++ks) {
                int off = (ks * 32 + g * 8) ^ (x7 << 4);
                a[mi][ks] = *(const long*)(As8 + ar * 128 + off);
                b[mi][ks] = *(const long*)(Bs8 + br * 128 + off);
            }
        }
        #pragma unroll
        for (int mi = 0; mi < 4; ++mi)
            #pragma unroll
            for (int ni = 0; ni < 4; ++ni)
                #pragma unroll
                for (int ks = 0; ks < 4; ++ks)
                    acc[mi][ni] = __builtin_amdgcn_mfma_f32_16x16x32_fp8_fp8(
                        a[mi][ks], b[ni][ks], acc[mi][ni], 0, 0, 0);
    }
    int ct[4];
    #pragma unroll
    for (int ni = 0; ni < 4; ++ni) ct[ni] = ct_s[wc * 64 + ni * 16 + l15];
    float cd[4] = {}, cn[4] = {};
    #pragma unroll
    for (int mi = 0; mi < 4; ++mi) {
        #pragma unroll
        for (int r = 0; r < 4; ++r) {
            int row = wr * 64 + mi * 16 + g * 4 + r;
            int rt = rt_s[row];
            float d = 0.f, n = 0.f;
            #pragma unroll
            for (int ni = 0; ni < 4; ++ni) {
                float v = __expf(TAU_F * acc[mi][ni][r]);
                float nv = (ct[ni] != rt) ? v : 0.f;
                d += v; n += nv;
                cd[ni] += v; cn[ni] += nv;
            }
            #pragma unroll
            for (int mm = 1; mm < 16; mm <<= 1) {
                d += __shfl_xor(d, mm);
                n += __shfl_xor(n, mm);
            }
            if (l15 == 0) {
                pden[bx * B_N + rb + row] = d;   // slot bx, plain store
                pnom[bx * B_N + rb + row] = n;
            }
        }
    }
    if (!diag) {
        #pragma unroll
        for (int ni = 0; ni < 4; ++ni) {
            float d = cd[ni], n = cn[ni];
            d += __shfl_xor(d, 16); d += __shfl_xor(d, 32);
            n += __shfl_xor(n, 16); n += __shfl_xor(n, 32);
            if (g == 0) {
                int col = wc * 64 + ni * 16 + l15;
                pden[by * B_N + cb + col] = d;   // slot by, plain store
                pnom[by * B_N + cb + col] = n;
            }
        }
    }
}

// ---------------------------------------------------------------------------
// aug: one 8-lane group per (j,item); fp8 phi gather (L2-resident), plain
// stores to sexp. (Round-11 A/B: forced MLP neutral -> this is the floor.)
__global__ __launch_bounds__(256, 4) void aug_dots_kernel(
        const ushort* __restrict__ e2b, const unsigned char* __restrict__ phif8,
        const int* __restrict__ neg_idx, float* __restrict__ sexp) {
    int gi = blockIdx.x * 32 + (threadIdx.x >> 3);
    int sub = threadIdx.x & 7;
    int j = gi / ITEMS_J;
    int idx = gi - j * ITEMS_J;
    int tgt = (idx == 0) ? j : neg_idx[(size_t)j * N_NEGS + idx - 1];
    const ushort* e        = e2b   + (size_t)j   * D_N + sub * 8;
    const unsigned char* p = phif8 + (size_t)tgt * D_N + sub * 8;

    uint2 pv[8]; bf16x8 ev[8];
    #pragma unroll
    for (int k = 0; k < 8; ++k) {
        pv[k] = *(const uint2*)(p + k * 64);
        ev[k] = *(const bf16x8*)(e + k * 64);
    }
    float s0 = 0.f, s1 = 0.f;
    #pragma unroll
    for (int k = 0; k < 8; ++k) {
        f32x2 a0 = __builtin_amdgcn_cvt_pk_f32_fp8((int)pv[k].x, false);
        f32x2 a1 = __builtin_amdgcn_cvt_pk_f32_fp8((int)pv[k].x, true);
        f32x2 a2 = __builtin_amdgcn_cvt_pk_f32_fp8((int)pv[k].y, false);
        f32x2 a3 = __builtin_amdgcn_cvt_pk_f32_fp8((int)pv[k].y, true);
        s0 += bf2f(ev[k][0]) * a0.x + bf2f(ev[k][1]) * a0.y
            + bf2f(ev[k][2]) * a1.x + bf2f(ev[k][3]) * a1.y;
        s1 += bf2f(ev[k][4]) * a2.x + bf2f(ev[k][5]) * a2.y
            + bf2f(ev[k][6]) * a3.x + bf2f(ev[k][7]) * a3.y;
    }
    float s = s0 + s1;
    s += __shfl_xor(s, 1);
    s += __shfl_xor(s, 2);
    s += __shfl_xor(s, 4);
    if (sub == 0) sexp[(size_t)j * SEXP_LD + idx] = __expf(TAU_F * s);
}

// ---------------------------------------------------------------------------
// final1: 64 blocks; per j: reduce sexp row -> L_a, reduce 32 den/nom
// partial slots -> L_s; write per-block {La,Ls} partials (plain stores).
__global__ __launch_bounds__(256) void final1_kernel(
        const float* __restrict__ sexp, const float* __restrict__ pden,
        const float* __restrict__ pnom, const int* __restrict__ tag,
        float* __restrict__ stat) {
    __shared__ float wla[4], wls[4];
    int lane = threadIdx.x & 63, w = threadIdx.x >> 6;
    int j0 = blockIdx.x * 64;
    float la = 0.f, ls = 0.f;
    for (int jj = w; jj < 64; jj += 4) {
        int j = j0 + jj;
        float v0 = sexp[(size_t)j * SEXP_LD + lane];
        float v1 = (lane + 64 < ITEMS_J) ? sexp[(size_t)j * SEXP_LD + lane + 64] : 0.f;
        float pos = __shfl(v0, 0);
        float ns = ((lane >= 1) ? v0 : 0.f) + v1;
        float d = (lane < 32) ? pden[lane * B_N + j] : 0.f;
        float n = (lane < 32) ? pnom[lane * B_N + j] : 0.f;
        #pragma unroll
        for (int mm = 32; mm; mm >>= 1) {
            ns += __shfl_xor(ns, mm);
            d  += __shfl_xor(d, mm);
            n  += __shfl_xor(n, mm);
        }
        if (lane == 0) {
            float La = logf(pos / (EPS_F + pos + ns));
            if (La == La) la += La;
            float Ls = logf(n / (d + EPS_F));
            bool valid = (stat[S_HIST + tag[j]] < (float)B_N) && (Ls == Ls);
            if (valid) ls += Ls;
        }
    }
    if (lane == 0) { wla[w] = la; wls[w] = ls; }
    __syncthreads();
    if (threadIdx.x == 0) {
        stat[S_FIN + blockIdx.x * 2]     = wla[0] + wla[1] + wla[2] + wla[3];
        stat[S_FIN + blockIdx.x * 2 + 1] = wls[0] + wls[1] + wls[2] + wls[3];
    }
}

// ---------------------------------------------------------------------------
__global__ __launch_bounds__(256) void final2_kernel(
        const float* __restrict__ stat, float* __restrict__ out) {
    __shared__ float sred[4];
    int t = threadIdx.x;
    float w2 = block_sum256(t < 128 ? stat[S_W2P + t] : 0.f, sred);
    float la = block_sum256(t < 64 ? stat[S_FIN + 2 * t] : 0.f, sred);
    float ls = block_sum256(t < 64 ? stat[S_FIN + 2 * t + 1] : 0.f, sred);
    if (t == 0) {
        out[0] = stat[S_MSE] / (float)B_N;
        out[1] = REGW_F * (sqrtf(w2) + sqrtf(stat[S_B2]) +
                           sqrtf(stat[S_WH2]) + sqrtf(stat[S_BH2]));
        out[2] = -la / (float)B_N;
        out[3] = -ls / (float)B_N;
    }
}

// ---------------------------------------------------------------------------
extern "C" void kernel_launch(void* const* d_in, const int* in_sizes, int n_in,
                              void* d_out, int out_size, void* d_ws, size_t ws_size,
                              hipStream_t stream) {
    const float* e1       = (const float*)d_in[0];
    const float* e2       = (const float*)d_in[1];
    const float* y_pred   = (const float*)d_in[2];
    const float* y_target = (const float*)d_in[3];
    const float* W_e2     = (const float*)d_in[4];
    const float* b_e2     = (const float*)d_in[5];
    const float* W_head   = (const float*)d_in[6];
    const float* b_head   = (const float*)d_in[7];
    const float* lmbda    = (const float*)d_in[8];
    const int*   mix_idx  = (const int*)d_in[9];
    const int*   neg_idx  = (const int*)d_in[10];
    const int*   dtag     = (const int*)d_in[11];
    char* base = (char*)d_ws;
    float* out = (float*)d_out;
    unsigned char* phif8 = (unsigned char*)(base + PHIF8_B);
    ushort* e2b  = (ushort*)(base + E2B_B);
    ushort* wtb  = (ushort*)(base + WTB_B);
    ushort* augb = (ushort*)(base + AUGB_B);
    float*  sexp = (float*)(base + SEXP_B);
    float*  pden = (float*)(base + PDEN_B);
    float*  pnom = (float*)(base + PNOM_B);
    unsigned char* e2f8 = (unsigned char*)(base + E2F8_B);
    float*  stat = (float*)(base + STAT_B);

    prep_kernel<<<dim3(1024, 5), dim3(256), 0, stream>>>(
        y_pred, y_target, W_e2, b_e2, W_head, b_head, e2, e1, lmbda, mix_idx,
        dtag, wtb, e2b, augb, e2f8, stat);
    phi_kernel<<<dim3(D_N / 128, B_N / 64), dim3(256), 0, stream>>>(
        augb, wtb, b_e2, phif8);
    supp_kernel<<<dim3(528), dim3(256), 0, stream>>>(e2f8, dtag, pden, pnom);
    aug_dots_kernel<<<dim3(B_N * ITEMS_J / 32), dim3(256), 0, stream>>>(
        e2b, phif8, neg_idx, sexp);
    final1_kernel<<<dim3(64), dim3(256), 0, stream>>>(
        sexp, pden, pnom, dtag, stat);
    final2_kernel<<<dim3(1), dim3(256), 0, stream>>>(stat, out);
}

// Round 15
// 81.149 us; speedup vs baseline: 1.2472x; 1.0841x over previous
//
#include <hip/hip_runtime.h>
#include <hip/hip_bf16.h>
#include <math.h>

#define B_N 4096
#define D_N 512
#define N_NEGS 100
#define N_DOM 8
#define TAU_F 1e-4f
#define EPS_F 1e-6f
#define REGW_F 1e-4f
#define ITEMS_J 101
#define SEXP_LD 102
#define SUPP_NB 528

typedef __attribute__((ext_vector_type(8))) short bf16x8;
typedef __attribute__((ext_vector_type(4))) float f32x4;
typedef __attribute__((ext_vector_type(2))) float f32x2;

// ---- workspace layout (byte offsets). ~15.5 MB used, all plain-store init.
#define PHIF8_B 0u                      // fp8 phi [4096][512]        (2 MB)
#define E2B_B   (2u << 20)              // bf16 e2 [4096][512]        (4 MB)
#define WTB_B   (6u << 20)              // bf16 W^T [512][512]        (0.5 MB)
#define AUGB_B  (WTB_B + (1u << 19))    // bf16 mixup(e1) [4096][512] (4 MB)
#define SEXP_B  (AUGB_B + (4u << 20))   // f32 [4096][102]            (1.7 MB)
#define PDEN_B  (SEXP_B + (2u << 20))   // f32 [32][4096] den partials (512 KB)
#define PNOM_B  (PDEN_B + (1u << 19))   // f32 [32][4096] nom partials (512 KB)
#define E2F8_B  (PNOM_B + (1u << 19))   // fp8 e2 [4096][512]         (2 MB)
#define STAT_B  (E2F8_B + (2u << 20))   // stats floats
// stat region (float indices) — every slot plain-stored each call, no init
#define S_MSE  0
#define S_B2   1
#define S_WH2  2
#define S_BH2  3
#define S_HIST 8                        // 8 domain counts (as float)
#define S_W2P  16                       // 64 ||W||^2 partials (one per wtb tile)
#define S_FIN  144                      // 64 x {La, Ls} block partials

// ---------------------------------------------------------------------------
__device__ __forceinline__ ushort f2bf(float f) {
    union { __hip_bfloat16 h; ushort u; } v;
    v.h = __float2bfloat16(f);
    return v.u;
}
__device__ __forceinline__ float bf2f(short s) {
    return __uint_as_float(((uint)(ushort)s) << 16);
}

// global->LDS async staging (linear LDS dest, pre-swizzled global source so
// reads XOR-swizzle; T2/m201 pattern).
__device__ __forceinline__ void stage_bf16_tile(
        const ushort* __restrict__ g, int row0, int col0, int ldg,
        ushort* lds, int t) {
    int wid = t >> 6, lane = t & 63;
    #pragma unroll
    for (int i = 0; i < 4; ++i) {
        int p = i * 4096 + wid * 1024 + lane * 16;
        int row = p >> 7;
        int colb = (p & 127) ^ ((row & 7) << 4);
        const ushort* src = g + (size_t)(row0 + row) * ldg + col0 + (colb >> 1);
        ushort* dst = lds + (i * 4096 + wid * 1024) / 2;
        __builtin_amdgcn_global_load_lds(
            (const __attribute__((address_space(1))) unsigned int*)src,
            (__attribute__((address_space(3))) unsigned int*)dst, 16, 0, 0);
    }
}
// 64x64 bf16 variant (8 KB)
__device__ __forceinline__ void stage_bf16_tile64(
        const ushort* __restrict__ g, int row0, int col0, int ldg,
        ushort* lds, int t) {
    int wid = t >> 6, lane = t & 63;
    #pragma unroll
    for (int i = 0; i < 2; ++i) {
        int p = i * 4096 + wid * 1024 + lane * 16;
        int row = p >> 7;
        int colb = (p & 127) ^ ((row & 7) << 4);
        const ushort* src = g + (size_t)(row0 + row) * ldg + col0 + (colb >> 1);
        ushort* dst = lds + (i * 4096 + wid * 1024) / 2;
        __builtin_amdgcn_global_load_lds(
            (const __attribute__((address_space(1))) unsigned int*)src,
            (__attribute__((address_space(3))) unsigned int*)dst, 16, 0, 0);
    }
}
// 128x128 fp8 tile (16 KB): rows are 128 B -> identical byte arithmetic.
__device__ __forceinline__ void stage_fp8_tile(
        const unsigned char* __restrict__ g, int row0, int col0, int ldg,
        unsigned char* lds, int t) {
    int wid = t >> 6, lane = t & 63;
    #pragma unroll
    for (int i = 0; i < 4; ++i) {
        int p = i * 4096 + wid * 1024 + lane * 16;
        int row = p >> 7;
        int colb = (p & 127) ^ ((row & 7) << 4);
        const unsigned char* src = g + (size_t)(row0 + row) * ldg + col0 + colb;
        unsigned char* dst = lds + i * 4096 + wid * 1024;
        __builtin_amdgcn_global_load_lds(
            (const __attribute__((address_space(1))) unsigned int*)src,
            (__attribute__((address_space(3))) unsigned int*)dst, 16, 0, 0);
    }
}

// ---------------------------------------------------------------------------
__device__ __forceinline__ float block_sum256(float v, float* sred) {
    #pragma unroll
    for (int m = 32; m; m >>= 1) v += __shfl_xor(v, m, 64);
    int lane = threadIdx.x & 63, wid = threadIdx.x >> 6;
    __syncthreads();
    if (lane == 0) sred[wid] = v;
    __syncthreads();
    float s = 0.0f;
    if (threadIdx.x == 0) s = sred[0] + sred[1] + sred[2] + sred[3];
    return s;
}

// ---------------------------------------------------------------------------
// prep: all input-only work, one flat grid, NO atomics, inputs read ONCE.
//   x <  1024: e2 -> bf16 AND fp8 (single read)
//   x < 2048 : mixup(e1) -> bf16 augb
//   x < 2112 : wtb transpose tile + ||W||^2 partial (single read of W)
//   x == 2112: mse   x == 2113: small norms   x == 2114: histogram
__global__ __launch_bounds__(256) void prep_kernel(
        const float* __restrict__ y_pred, const float* __restrict__ y_target,
        const float* __restrict__ W_e2, const float* __restrict__ b_e2,
        const float* __restrict__ W_head, const float* __restrict__ b_head,
        const float* __restrict__ e2, const float* __restrict__ e1,
        const float* __restrict__ lmbda, const int* __restrict__ mix,
        const int* __restrict__ tag,
        ushort* __restrict__ wtb, ushort* __restrict__ e2b,
        ushort* __restrict__ augb, unsigned char* __restrict__ e2f8,
        float* __restrict__ stat) {
    int t = threadIdx.x, x = blockIdx.x;
    if (x < 1024) {                       // e2 -> bf16 + fp8, one read
        int i = (x * 256 + t) * 8;
        f32x4 v0 = *(const f32x4*)(e2 + i);
        f32x4 v1 = *(const f32x4*)(e2 + i + 4);
        bf16x8 o;
        o[0] = (short)f2bf(v0.x); o[1] = (short)f2bf(v0.y);
        o[2] = (short)f2bf(v0.z); o[3] = (short)f2bf(v0.w);
        o[4] = (short)f2bf(v1.x); o[5] = (short)f2bf(v1.y);
        o[6] = (short)f2bf(v1.z); o[7] = (short)f2bf(v1.w);
        *(bf16x8*)(e2b + i) = o;
        int w0 = 0, w1 = 0;
        w0 = __builtin_amdgcn_cvt_pk_fp8_f32(v0.x, v0.y, w0, false);
        w0 = __builtin_amdgcn_cvt_pk_fp8_f32(v0.z, v0.w, w0, true);
        w1 = __builtin_amdgcn_cvt_pk_fp8_f32(v1.x, v1.y, w1, false);
        w1 = __builtin_amdgcn_cvt_pk_fp8_f32(v1.z, v1.w, w1, true);
        *(int2*)(e2f8 + i) = make_int2(w0, w1);
        return;
    }
    if (x < 2048) {                       // mixup -> bf16 augb
        int i = ((x - 1024) * 256 + t) * 8;
        int row = i >> 9, col = i & 511;
        float lam = lmbda[row], oml = 1.0f - lam;
        const float* a = e1 + (size_t)row * D_N + col;
        const float* c = e1 + (size_t)mix[row] * D_N + col;
        f32x4 a0 = *(const f32x4*)a, a1 = *(const f32x4*)(a + 4);
        f32x4 c0 = *(const f32x4*)c, c1 = *(const f32x4*)(c + 4);
        bf16x8 o;
        o[0] = (short)f2bf(lam * a0.x + oml * c0.x);
        o[1] = (short)f2bf(lam * a0.y + oml * c0.y);
        o[2] = (short)f2bf(lam * a0.z + oml * c0.z);
        o[3] = (short)f2bf(lam * a0.w + oml * c0.w);
        o[4] = (short)f2bf(lam * a1.x + oml * c1.x);
        o[5] = (short)f2bf(lam * a1.y + oml * c1.y);
        o[6] = (short)f2bf(lam * a1.z + oml * c1.z);
        o[7] = (short)f2bf(lam * a1.w + oml * c1.w);
        *(bf16x8*)(augb + i) = o;
        return;
    }
    if (x < 2112) {                       // wtb tile + W2 partial, one read
        int xx = x - 2048;                // 0..63
        __shared__ float tile[64][65];
        __shared__ float sred[4];
        int k0 = (xx >> 3) * 64, n0 = (xx & 7) * 64;
        int r = t >> 4, c = (t & 15) * 4;
        float ss = 0.0f;
        #pragma unroll
        for (int i = 0; i < 4; ++i) {
            f32x4 v = *(const f32x4*)(W_e2 + (size_t)(k0 + r + i * 16) * D_N + n0 + c);
            tile[r + i * 16][c]     = v.x;
            tile[r + i * 16][c + 1] = v.y;
            tile[r + i * 16][c + 2] = v.z;
            tile[r + i * 16][c + 3] = v.w;
            ss += v.x * v.x + v.y * v.y + v.z * v.z + v.w * v.w;
        }
        __syncthreads();
        int nl = t >> 2, kq = (t & 3) * 16;
        bf16x8 o0, o1;
        #pragma unroll
        for (int q = 0; q < 8; ++q) o0[q] = (short)f2bf(tile[kq + q][nl]);
        #pragma unroll
        for (int q = 0; q < 8; ++q) o1[q] = (short)f2bf(tile[kq + 8 + q][nl]);
        ushort* dst = wtb + (size_t)(n0 + nl) * D_N + k0 + kq;
        *(bf16x8*)dst = o0;
        *(bf16x8*)(dst + 8) = o1;
        float s = block_sum256(ss, sred);
        if (t == 0) stat[S_W2P + xx] = s;
        return;
    }
    __shared__ float sred[4];
    if (x == 2112) {
        float s = 0.0f;
        for (int i = t; i < B_N; i += 256) {
            float d = y_pred[i] - y_target[i]; s += d * d;
        }
        s = block_sum256(s, sred);
        if (t == 0) stat[S_MSE] = s;
    } else if (x == 2113) {
        float v1 = b_e2[t], v2 = b_e2[t + 256];
        float s = block_sum256(v1 * v1 + v2 * v2, sred);
        if (t == 0) stat[S_B2] = s;
        v1 = W_head[t]; v2 = W_head[t + 256];
        s = block_sum256(v1 * v1 + v2 * v2, sred);
        if (t == 0) {
            stat[S_WH2] = s;
            stat[S_BH2] = b_head[0] * b_head[0];
        }
    } else if (x == 2114) {
        __shared__ int h[N_DOM];
        if (t < N_DOM) h[t] = 0;
        __syncthreads();
        for (int i = t; i < B_N; i += 256) atomicAdd(&h[tag[i]], 1);
        __syncthreads();
        if (t < N_DOM) stat[S_HIST + t] = (float)h[t];
    }
}

// ---------------------------------------------------------------------------
// gemm: HOMOGENEOUS fusion of supp (blocks 0..527, fp8 BK=128 triangular
// Gram) and phi (blocks 528..783, bf16 64x128 GEMM -> fp8 out). Both are
// 256-thread MFMA kernels at the same ~4 blocks/CU operating point — unlike
// round-13's heterogeneous fusion, neither population is starved. Supp
// blocks (2x longer) dispatch first; phi fills in behind them.
__global__ __launch_bounds__(256) void gemm_kernel(
        const unsigned char* __restrict__ e2f8, const int* __restrict__ tag,
        const ushort* __restrict__ augb, const ushort* __restrict__ wtb,
        const float* __restrict__ bvec,
        float* __restrict__ pden, float* __restrict__ pnom,
        unsigned char* __restrict__ phif8) {
    __shared__ unsigned char As8[128 * 128];
    __shared__ unsigned char Bs8[128 * 128];
    __shared__ int rt_s[128], ct_s[128];
    int t = threadIdx.x;
    int lane = t & 63, wid = t >> 6;
    int l15 = lane & 15, g = lane >> 4, x7 = l15 & 7;
    int wr = wid >> 1, wc = wid & 1;

    if (blockIdx.x >= SUPP_NB) {
        // ---------------- phi part (bf16, 64x128 tile) ----------------
        int bid = blockIdx.x - SUPP_NB;            // 0..255
        int rb = (bid >> 2) * 64, cb = (bid & 3) * 128;
        ushort* As = (ushort*)As8;                 // 8 KB of the 16 KB buffer
        ushort* Bs = (ushort*)Bs8;                 // 16 KB exactly
        f32x4 acc[2][4] = {};
        for (int kk = 0; kk < D_N; kk += 64) {
            __syncthreads();
            stage_bf16_tile64(augb, rb, kk, D_N, As, t);
            stage_bf16_tile  (wtb,  cb, kk, D_N, Bs, t);
            __syncthreads();
            bf16x8 a[2][2], b[4][2];
            #pragma unroll
            for (int mi = 0; mi < 2; ++mi)
                #pragma unroll
                for (int ks = 0; ks < 2; ++ks) {
                    int ar = wr * 32 + mi * 16 + l15;
                    a[mi][ks] = *(const bf16x8*)((const char*)As +
                        ar * 128 + (((ks << 2) | g) ^ x7) * 16);
                }
            #pragma unroll
            for (int ni = 0; ni < 4; ++ni)
                #pragma unroll
                for (int ks = 0; ks < 2; ++ks) {
                    int br = wc * 64 + ni * 16 + l15;
                    b[ni][ks] = *(const bf16x8*)((const char*)Bs +
                        br * 128 + (((ks << 2) | g) ^ x7) * 16);
                }
            #pragma unroll
            for (int mi = 0; mi < 2; ++mi)
                #pragma unroll
                for (int ni = 0; ni < 4; ++ni)
                    #pragma unroll
                    for (int ks = 0; ks < 2; ++ks)
                        acc[mi][ni] = __builtin_amdgcn_mfma_f32_16x16x32_bf16(
                            a[mi][ks], b[ni][ks], acc[mi][ni], 0, 0, 0);
        }
        float bb[4];
        #pragma unroll
        for (int ni = 0; ni < 4; ++ni) bb[ni] = bvec[cb + wc * 64 + ni * 16 + l15];
        #pragma unroll
        for (int mi = 0; mi < 2; ++mi)
            #pragma unroll
            for (int r = 0; r < 4; ++r) {
                int row = rb + wr * 32 + mi * 16 + g * 4 + r;
                #pragma unroll
                for (int ni = 0; ni < 4; ++ni) {
                    int col = cb + wc * 64 + ni * 16 + l15;
                    float v = acc[mi][ni][r] + bb[ni];
                    phif8[(size_t)row * D_N + col] = (unsigned char)
                        (__builtin_amdgcn_cvt_pk_fp8_f32(v, v, 0, false) & 0xff);
                }
            }
        return;
    }

    // ---------------- supp part (fp8 e4m3, BK=128 triangular) ----------------
    int tid = blockIdx.x;                      // 0..527
    int sw = (tid & 7) * 66 + (tid >> 3);      // XCD swizzle (528 = 8*66)
    int by = (int)((sqrtf(8.0f * (float)sw + 1.0f) - 1.0f) * 0.5f);
    while ((by + 1) * (by + 2) / 2 <= sw) ++by;
    while (by * (by + 1) / 2 > sw) --by;
    int bx = sw - by * (by + 1) / 2;           // bx <= by
    bool diag = (bx == by);
    int rb = by * 128, cb = bx * 128;
    if (t < 128) rt_s[t] = tag[rb + t];
    else         ct_s[t - 128] = tag[cb + t - 128];

    f32x4 acc[4][4] = {};
    for (int kk = 0; kk < D_N; kk += 128) {
        __syncthreads();
        stage_fp8_tile(e2f8, rb, kk, D_N, As8, t);
        stage_fp8_tile(e2f8, cb, kk, D_N, Bs8, t);
        __syncthreads();
        long a[4][4], b[4][4];
        #pragma unroll
        for (int mi = 0; mi < 4; ++mi) {
            int ar = wr * 64 + mi * 16 + l15;
            int br = wc * 64 + mi * 16 + l15;
            #pragma unroll
            for (int ks = 0; ks < 4; ++ks) {
                int off = (ks * 32 + g * 8) ^ (x7 << 4);
                a[mi][ks] = *(const long*)(As8 + ar * 128 + off);
                b[mi][ks] = *(const long*)(Bs8 + br * 128 + off);
            }
        }
        #pragma unroll
        for (int mi = 0; mi < 4; ++mi)
            #pragma unroll
            for (int ni = 0; ni < 4; ++ni)
                #pragma unroll
                for (int ks = 0; ks < 4; ++ks)
                    acc[mi][ni] = __builtin_amdgcn_mfma_f32_16x16x32_fp8_fp8(
                        a[mi][ks], b[ni][ks], acc[mi][ni], 0, 0, 0);
    }
    int ct[4];
    #pragma unroll
    for (int ni = 0; ni < 4; ++ni) ct[ni] = ct_s[wc * 64 + ni * 16 + l15];
    float cd[4] = {}, cn[4] = {};
    #pragma unroll
    for (int mi = 0; mi < 4; ++mi) {
        #pragma unroll
        for (int r = 0; r < 4; ++r) {
            int row = wr * 64 + mi * 16 + g * 4 + r;
            int rt = rt_s[row];
            float d = 0.f, n = 0.f;
            #pragma unroll
            for (int ni = 0; ni < 4; ++ni) {
                float v = __expf(TAU_F * acc[mi][ni][r]);
                float nv = (ct[ni] != rt) ? v : 0.f;
                d += v; n += nv;
                cd[ni] += v; cn[ni] += nv;
            }
            #pragma unroll
            for (int mm = 1; mm < 16; mm <<= 1) {
                d += __shfl_xor(d, mm);
                n += __shfl_xor(n, mm);
            }
            if (l15 == 0) {
                pden[bx * B_N + rb + row] = d;   // slot bx, plain store
                pnom[bx * B_N + rb + row] = n;
            }
        }
    }
    if (!diag) {
        #pragma unroll
        for (int ni = 0; ni < 4; ++ni) {
            float d = cd[ni], n = cn[ni];
            d += __shfl_xor(d, 16); d += __shfl_xor(d, 32);
            n += __shfl_xor(n, 16); n += __shfl_xor(n, 32);
            if (g == 0) {
                int col = wc * 64 + ni * 16 + l15;
                pden[by * B_N + cb + col] = d;   // slot by, plain store
                pnom[by * B_N + cb + col] = n;
            }
        }
    }
}

// ---------------------------------------------------------------------------
// aug: one 8-lane group per (j,item); fp8 phi gather (L2-resident), plain
// stores to sexp. (Round-11 A/B: forced MLP neutral -> this is the floor.)
__global__ __launch_bounds__(256, 4) void aug_dots_kernel(
        const ushort* __restrict__ e2b, const unsigned char* __restrict__ phif8,
        const int* __restrict__ neg_idx, float* __restrict__ sexp) {
    int gi = blockIdx.x * 32 + (threadIdx.x >> 3);
    int sub = threadIdx.x & 7;
    int j = gi / ITEMS_J;
    int idx = gi - j * ITEMS_J;
    int tgt = (idx == 0) ? j : neg_idx[(size_t)j * N_NEGS + idx - 1];
    const ushort* e        = e2b   + (size_t)j   * D_N + sub * 8;
    const unsigned char* p = phif8 + (size_t)tgt * D_N + sub * 8;

    uint2 pv[8]; bf16x8 ev[8];
    #pragma unroll
    for (int k = 0; k < 8; ++k) {
        pv[k] = *(const uint2*)(p + k * 64);
        ev[k] = *(const bf16x8*)(e + k * 64);
    }
    float s0 = 0.f, s1 = 0.f;
    #pragma unroll
    for (int k = 0; k < 8; ++k) {
        f32x2 a0 = __builtin_amdgcn_cvt_pk_f32_fp8((int)pv[k].x, false);
        f32x2 a1 = __builtin_amdgcn_cvt_pk_f32_fp8((int)pv[k].x, true);
        f32x2 a2 = __builtin_amdgcn_cvt_pk_f32_fp8((int)pv[k].y, false);
        f32x2 a3 = __builtin_amdgcn_cvt_pk_f32_fp8((int)pv[k].y, true);
        s0 += bf2f(ev[k][0]) * a0.x + bf2f(ev[k][1]) * a0.y
            + bf2f(ev[k][2]) * a1.x + bf2f(ev[k][3]) * a1.y;
        s1 += bf2f(ev[k][4]) * a2.x + bf2f(ev[k][5]) * a2.y
            + bf2f(ev[k][6]) * a3.x + bf2f(ev[k][7]) * a3.y;
    }
    float s = s0 + s1;
    s += __shfl_xor(s, 1);
    s += __shfl_xor(s, 2);
    s += __shfl_xor(s, 4);
    if (sub == 0) sexp[(size_t)j * SEXP_LD + idx] = __expf(TAU_F * s);
}

// ---------------------------------------------------------------------------
// final1: 64 blocks; per j: reduce sexp row -> L_a, reduce 32 den/nom
// partial slots -> L_s; write per-block {La,Ls} partials (plain stores).
__global__ __launch_bounds__(256) void final1_kernel(
        const float* __restrict__ sexp, const float* __restrict__ pden,
        const float* __restrict__ pnom, const int* __restrict__ tag,
        float* __restrict__ stat) {
    __shared__ float wla[4], wls[4];
    int lane = threadIdx.x & 63, w = threadIdx.x >> 6;
    int j0 = blockIdx.x * 64;
    float la = 0.f, ls = 0.f;
    for (int jj = w; jj < 64; jj += 4) {
        int j = j0 + jj;
        float v0 = sexp[(size_t)j * SEXP_LD + lane];
        float v1 = (lane + 64 < ITEMS_J) ? sexp[(size_t)j * SEXP_LD + lane + 64] : 0.f;
        float pos = __shfl(v0, 0);
        float ns = ((lane >= 1) ? v0 : 0.f) + v1;
        float d = (lane < 32) ? pden[lane * B_N + j] : 0.f;
        float n = (lane < 32) ? pnom[lane * B_N + j] : 0.f;
        #pragma unroll
        for (int mm = 32; mm; mm >>= 1) {
            ns += __shfl_xor(ns, mm);
            d  += __shfl_xor(d, mm);
            n  += __shfl_xor(n, mm);
        }
        if (lane == 0) {
            float La = logf(pos / (EPS_F + pos + ns));
            if (La == La) la += La;
            float Ls = logf(n / (d + EPS_F));
            bool valid = (stat[S_HIST + tag[j]] < (float)B_N) && (Ls == Ls);
            if (valid) ls += Ls;
        }
    }
    if (lane == 0) { wla[w] = la; wls[w] = ls; }
    __syncthreads();
    if (threadIdx.x == 0) {
        stat[S_FIN + blockIdx.x * 2]     = wla[0] + wla[1] + wla[2] + wla[3];
        stat[S_FIN + blockIdx.x * 2 + 1] = wls[0] + wls[1] + wls[2] + wls[3];
    }
}

// ---------------------------------------------------------------------------
__global__ __launch_bounds__(256) void final2_kernel(
        const float* __restrict__ stat, float* __restrict__ out) {
    __shared__ float sred[4];
    int t = threadIdx.x;
    float w2 = block_sum256(t < 64 ? stat[S_W2P + t] : 0.f, sred);
    float la = block_sum256(t < 64 ? stat[S_FIN + 2 * t] : 0.f, sred);
    float ls = block_sum256(t < 64 ? stat[S_FIN + 2 * t + 1] : 0.f, sred);
    if (t == 0) {
        out[0] = stat[S_MSE] / (float)B_N;
        out[1] = REGW_F * (sqrtf(w2) + sqrtf(stat[S_B2]) +
                           sqrtf(stat[S_WH2]) + sqrtf(stat[S_BH2]));
        out[2] = -la / (float)B_N;
        out[3] = -ls / (float)B_N;
    }
}

// ---------------------------------------------------------------------------
extern "C" void kernel_launch(void* const* d_in, const int* in_sizes, int n_in,
                              void* d_out, int out_size, void* d_ws, size_t ws_size,
                              hipStream_t stream) {
    const float* e1       = (const float*)d_in[0];
    const float* e2       = (const float*)d_in[1];
    const float* y_pred   = (const float*)d_in[2];
    const float* y_target = (const float*)d_in[3];
    const float* W_e2     = (const float*)d_in[4];
    const float* b_e2     = (const float*)d_in[5];
    const float* W_head   = (const float*)d_in[6];
    const float* b_head   = (const float*)d_in[7];
    const float* lmbda    = (const float*)d_in[8];
    const int*   mix_idx  = (const int*)d_in[9];
    const int*   neg_idx  = (const int*)d_in[10];
    const int*   dtag     = (const int*)d_in[11];
    char* base = (char*)d_ws;
    float* out = (float*)d_out;
    unsigned char* phif8 = (unsigned char*)(base + PHIF8_B);
    ushort* e2b  = (ushort*)(base + E2B_B);
    ushort* wtb  = (ushort*)(base + WTB_B);
    ushort* augb = (ushort*)(base + AUGB_B);
    float*  sexp = (float*)(base + SEXP_B);
    float*  pden = (float*)(base + PDEN_B);
    float*  pnom = (float*)(base + PNOM_B);
    unsigned char* e2f8 = (unsigned char*)(base + E2F8_B);
    float*  stat = (float*)(base + STAT_B);

    prep_kernel<<<dim3(2115), dim3(256), 0, stream>>>(
        y_pred, y_target, W_e2, b_e2, W_head, b_head, e2, e1, lmbda, mix_idx,
        dtag, wtb, e2b, augb, e2f8, stat);
    gemm_kernel<<<dim3(SUPP_NB + 256), dim3(256), 0, stream>>>(
        e2f8, dtag, augb, wtb, b_e2, pden, pnom, phif8);
    aug_dots_kernel<<<dim3(B_N * ITEMS_J / 32), dim3(256), 0, stream>>>(
        e2b, phif8, neg_idx, sexp);
    final1_kernel<<<dim3(64), dim3(256), 0, stream>>>(
        sexp, pden, pnom, dtag, stat);
    final2_kernel<<<dim3(1), dim3(256), 0, stream>>>(stat, out);
}

// Round 16
// 80.078 us; speedup vs baseline: 1.2639x; 1.0134x over previous
//
#include <hip/hip_runtime.h>
#include <hip/hip_bf16.h>
#include <math.h>

#define B_N 4096
#define D_N 512
#define N_NEGS 100
#define N_DOM 8
#define TAU_F 1e-4f
#define EPS_F 1e-6f
#define REGW_F 1e-4f
#define ITEMS_J 101
#define SEXP_LD 102
#define SUPP_NB 528

typedef __attribute__((ext_vector_type(8))) short bf16x8;
typedef __attribute__((ext_vector_type(4))) float f32x4;
typedef __attribute__((ext_vector_type(2))) float f32x2;

// ---- workspace layout (byte offsets). ~11.5 MB used, all plain-store init.
#define PHIF8_B 0u                      // fp8 phi [4096][512]        (2 MB)
#define E2F8_B  (2u << 20)              // fp8 e2  [4096][512]        (2 MB)
#define WTB_B   (4u << 20)              // bf16 W^T [512][512]        (0.5 MB)
#define AUGB_B  (WTB_B + (1u << 19))    // bf16 mixup(e1) [4096][512] (4 MB)
#define SEXP_B  (AUGB_B + (4u << 20))   // f32 [4096][102]            (1.7 MB)
#define PDEN_B  (SEXP_B + (2u << 20))   // f32 [32][4096] den partials (512 KB)
#define PNOM_B  (PDEN_B + (1u << 19))   // f32 [32][4096] nom partials (512 KB)
#define STAT_B  (PNOM_B + (1u << 19))   // stats floats
// stat region (float indices) — every slot plain-stored each call, no init
#define S_MSE  0
#define S_B2   1
#define S_WH2  2
#define S_BH2  3
#define S_HIST 8                        // 8 domain counts (as float)
#define S_W2P  16                       // 64 ||W||^2 partials (one per wtb tile)
#define S_FIN  144                      // 64 x {La, Ls} block partials

// ---------------------------------------------------------------------------
__device__ __forceinline__ ushort f2bf(float f) {
    union { __hip_bfloat16 h; ushort u; } v;
    v.h = __float2bfloat16(f);
    return v.u;
}

// global->LDS async staging (linear LDS dest, pre-swizzled global source so
// reads XOR-swizzle; T2/m201 pattern).
__device__ __forceinline__ void stage_bf16_tile(
        const ushort* __restrict__ g, int row0, int col0, int ldg,
        ushort* lds, int t) {
    int wid = t >> 6, lane = t & 63;
    #pragma unroll
    for (int i = 0; i < 4; ++i) {
        int p = i * 4096 + wid * 1024 + lane * 16;
        int row = p >> 7;
        int colb = (p & 127) ^ ((row & 7) << 4);
        const ushort* src = g + (size_t)(row0 + row) * ldg + col0 + (colb >> 1);
        ushort* dst = lds + (i * 4096 + wid * 1024) / 2;
        __builtin_amdgcn_global_load_lds(
            (const __attribute__((address_space(1))) unsigned int*)src,
            (__attribute__((address_space(3))) unsigned int*)dst, 16, 0, 0);
    }
}
// 64x64 bf16 variant (8 KB)
__device__ __forceinline__ void stage_bf16_tile64(
        const ushort* __restrict__ g, int row0, int col0, int ldg,
        ushort* lds, int t) {
    int wid = t >> 6, lane = t & 63;
    #pragma unroll
    for (int i = 0; i < 2; ++i) {
        int p = i * 4096 + wid * 1024 + lane * 16;
        int row = p >> 7;
        int colb = (p & 127) ^ ((row & 7) << 4);
        const ushort* src = g + (size_t)(row0 + row) * ldg + col0 + (colb >> 1);
        ushort* dst = lds + (i * 4096 + wid * 1024) / 2;
        __builtin_amdgcn_global_load_lds(
            (const __attribute__((address_space(1))) unsigned int*)src,
            (__attribute__((address_space(3))) unsigned int*)dst, 16, 0, 0);
    }
}
// 128x128 fp8 tile (16 KB): rows are 128 B -> identical byte arithmetic.
__device__ __forceinline__ void stage_fp8_tile(
        const unsigned char* __restrict__ g, int row0, int col0, int ldg,
        unsigned char* lds, int t) {
    int wid = t >> 6, lane = t & 63;
    #pragma unroll
    for (int i = 0; i < 4; ++i) {
        int p = i * 4096 + wid * 1024 + lane * 16;
        int row = p >> 7;
        int colb = (p & 127) ^ ((row & 7) << 4);
        const unsigned char* src = g + (size_t)(row0 + row) * ldg + col0 + colb;
        unsigned char* dst = lds + i * 4096 + wid * 1024;
        __builtin_amdgcn_global_load_lds(
            (const __attribute__((address_space(1))) unsigned int*)src,
            (__attribute__((address_space(3))) unsigned int*)dst, 16, 0, 0);
    }
}

// ---------------------------------------------------------------------------
__device__ __forceinline__ float block_sum256(float v, float* sred) {
    #pragma unroll
    for (int m = 32; m; m >>= 1) v += __shfl_xor(v, m, 64);
    int lane = threadIdx.x & 63, wid = threadIdx.x >> 6;
    __syncthreads();
    if (lane == 0) sred[wid] = v;
    __syncthreads();
    float s = 0.0f;
    if (threadIdx.x == 0) s = sred[0] + sred[1] + sred[2] + sred[3];
    return s;
}

// ---------------------------------------------------------------------------
// prep: all input-only work, one flat grid, NO atomics, inputs read ONCE.
//   x <  1024: e2 -> fp8 (single read; bf16 copy no longer needed)
//   x < 2048 : mixup(e1) -> bf16 augb
//   x < 2112 : wtb transpose tile + ||W||^2 partial (single read of W)
//   x == 2112: mse   x == 2113: small norms   x == 2114: histogram
__global__ __launch_bounds__(256) void prep_kernel(
        const float* __restrict__ y_pred, const float* __restrict__ y_target,
        const float* __restrict__ W_e2, const float* __restrict__ b_e2,
        const float* __restrict__ W_head, const float* __restrict__ b_head,
        const float* __restrict__ e2, const float* __restrict__ e1,
        const float* __restrict__ lmbda, const int* __restrict__ mix,
        const int* __restrict__ tag,
        ushort* __restrict__ wtb, ushort* __restrict__ augb,
        unsigned char* __restrict__ e2f8, float* __restrict__ stat) {
    int t = threadIdx.x, x = blockIdx.x;
    if (x < 1024) {                       // e2 -> fp8, one read
        int i = (x * 256 + t) * 8;
        f32x4 v0 = *(const f32x4*)(e2 + i);
        f32x4 v1 = *(const f32x4*)(e2 + i + 4);
        int w0 = 0, w1 = 0;
        w0 = __builtin_amdgcn_cvt_pk_fp8_f32(v0.x, v0.y, w0, false);
        w0 = __builtin_amdgcn_cvt_pk_fp8_f32(v0.z, v0.w, w0, true);
        w1 = __builtin_amdgcn_cvt_pk_fp8_f32(v1.x, v1.y, w1, false);
        w1 = __builtin_amdgcn_cvt_pk_fp8_f32(v1.z, v1.w, w1, true);
        *(int2*)(e2f8 + i) = make_int2(w0, w1);
        return;
    }
    if (x < 2048) {                       // mixup -> bf16 augb
        int i = ((x - 1024) * 256 + t) * 8;
        int row = i >> 9, col = i & 511;
        float lam = lmbda[row], oml = 1.0f - lam;
        const float* a = e1 + (size_t)row * D_N + col;
        const float* c = e1 + (size_t)mix[row] * D_N + col;
        f32x4 a0 = *(const f32x4*)a, a1 = *(const f32x4*)(a + 4);
        f32x4 c0 = *(const f32x4*)c, c1 = *(const f32x4*)(c + 4);
        bf16x8 o;
        o[0] = (short)f2bf(lam * a0.x + oml * c0.x);
        o[1] = (short)f2bf(lam * a0.y + oml * c0.y);
        o[2] = (short)f2bf(lam * a0.z + oml * c0.z);
        o[3] = (short)f2bf(lam * a0.w + oml * c0.w);
        o[4] = (short)f2bf(lam * a1.x + oml * c1.x);
        o[5] = (short)f2bf(lam * a1.y + oml * c1.y);
        o[6] = (short)f2bf(lam * a1.z + oml * c1.z);
        o[7] = (short)f2bf(lam * a1.w + oml * c1.w);
        *(bf16x8*)(augb + i) = o;
        return;
    }
    if (x < 2112) {                       // wtb tile + W2 partial, one read
        int xx = x - 2048;                // 0..63
        __shared__ float tile[64][65];
        __shared__ float sred[4];
        int k0 = (xx >> 3) * 64, n0 = (xx & 7) * 64;
        int r = t >> 4, c = (t & 15) * 4;
        float ss = 0.0f;
        #pragma unroll
        for (int i = 0; i < 4; ++i) {
            f32x4 v = *(const f32x4*)(W_e2 + (size_t)(k0 + r + i * 16) * D_N + n0 + c);
            tile[r + i * 16][c]     = v.x;
            tile[r + i * 16][c + 1] = v.y;
            tile[r + i * 16][c + 2] = v.z;
            tile[r + i * 16][c + 3] = v.w;
            ss += v.x * v.x + v.y * v.y + v.z * v.z + v.w * v.w;
        }
        __syncthreads();
        int nl = t >> 2, kq = (t & 3) * 16;
        bf16x8 o0, o1;
        #pragma unroll
        for (int q = 0; q < 8; ++q) o0[q] = (short)f2bf(tile[kq + q][nl]);
        #pragma unroll
        for (int q = 0; q < 8; ++q) o1[q] = (short)f2bf(tile[kq + 8 + q][nl]);
        ushort* dst = wtb + (size_t)(n0 + nl) * D_N + k0 + kq;
        *(bf16x8*)dst = o0;
        *(bf16x8*)(dst + 8) = o1;
        float s = block_sum256(ss, sred);
        if (t == 0) stat[S_W2P + xx] = s;
        return;
    }
    __shared__ float sred[4];
    if (x == 2112) {
        float s = 0.0f;
        for (int i = t; i < B_N; i += 256) {
            float d = y_pred[i] - y_target[i]; s += d * d;
        }
        s = block_sum256(s, sred);
        if (t == 0) stat[S_MSE] = s;
    } else if (x == 2113) {
        float v1 = b_e2[t], v2 = b_e2[t + 256];
        float s = block_sum256(v1 * v1 + v2 * v2, sred);
        if (t == 0) stat[S_B2] = s;
        v1 = W_head[t]; v2 = W_head[t + 256];
        s = block_sum256(v1 * v1 + v2 * v2, sred);
        if (t == 0) {
            stat[S_WH2] = s;
            stat[S_BH2] = b_head[0] * b_head[0];
        }
    } else if (x == 2114) {
        __shared__ int h[N_DOM];
        if (t < N_DOM) h[t] = 0;
        __syncthreads();
        for (int i = t; i < B_N; i += 256) atomicAdd(&h[tag[i]], 1);
        __syncthreads();
        if (t < N_DOM) stat[S_HIST + t] = (float)h[t];
    }
}

// ---------------------------------------------------------------------------
// gemm: HOMOGENEOUS fusion of supp (blocks 0..527, fp8 BK=128 triangular
// Gram) and phi (blocks 528..783, bf16 64x128 GEMM -> fp8 out).
__global__ __launch_bounds__(256) void gemm_kernel(
        const unsigned char* __restrict__ e2f8, const int* __restrict__ tag,
        const ushort* __restrict__ augb, const ushort* __restrict__ wtb,
        const float* __restrict__ bvec,
        float* __restrict__ pden, float* __restrict__ pnom,
        unsigned char* __restrict__ phif8) {
    __shared__ unsigned char As8[128 * 128];
    __shared__ unsigned char Bs8[128 * 128];
    __shared__ int rt_s[128], ct_s[128];
    int t = threadIdx.x;
    int lane = t & 63, wid = t >> 6;
    int l15 = lane & 15, g = lane >> 4, x7 = l15 & 7;
    int wr = wid >> 1, wc = wid & 1;

    if (blockIdx.x >= SUPP_NB) {
        // ---------------- phi part (bf16, 64x128 tile) ----------------
        int bid = blockIdx.x - SUPP_NB;            // 0..255
        int rb = (bid >> 2) * 64, cb = (bid & 3) * 128;
        ushort* As = (ushort*)As8;
        ushort* Bs = (ushort*)Bs8;
        f32x4 acc[2][4] = {};
        for (int kk = 0; kk < D_N; kk += 64) {
            __syncthreads();
            stage_bf16_tile64(augb, rb, kk, D_N, As, t);
            stage_bf16_tile  (wtb,  cb, kk, D_N, Bs, t);
            __syncthreads();
            bf16x8 a[2][2], b[4][2];
            #pragma unroll
            for (int mi = 0; mi < 2; ++mi)
                #pragma unroll
                for (int ks = 0; ks < 2; ++ks) {
                    int ar = wr * 32 + mi * 16 + l15;
                    a[mi][ks] = *(const bf16x8*)((const char*)As +
                        ar * 128 + (((ks << 2) | g) ^ x7) * 16);
                }
            #pragma unroll
            for (int ni = 0; ni < 4; ++ni)
                #pragma unroll
                for (int ks = 0; ks < 2; ++ks) {
                    int br = wc * 64 + ni * 16 + l15;
                    b[ni][ks] = *(const bf16x8*)((const char*)Bs +
                        br * 128 + (((ks << 2) | g) ^ x7) * 16);
                }
            #pragma unroll
            for (int mi = 0; mi < 2; ++mi)
                #pragma unroll
                for (int ni = 0; ni < 4; ++ni)
                    #pragma unroll
                    for (int ks = 0; ks < 2; ++ks)
                        acc[mi][ni] = __builtin_amdgcn_mfma_f32_16x16x32_bf16(
                            a[mi][ks], b[ni][ks], acc[mi][ni], 0, 0, 0);
        }
        float bb[4];
        #pragma unroll
        for (int ni = 0; ni < 4; ++ni) bb[ni] = bvec[cb + wc * 64 + ni * 16 + l15];
        #pragma unroll
        for (int mi = 0; mi < 2; ++mi)
            #pragma unroll
            for (int r = 0; r < 4; ++r) {
                int row = rb + wr * 32 + mi * 16 + g * 4 + r;
                #pragma unroll
                for (int ni = 0; ni < 4; ++ni) {
                    int col = cb + wc * 64 + ni * 16 + l15;
                    float v = acc[mi][ni][r] + bb[ni];
                    phif8[(size_t)row * D_N + col] = (unsigned char)
                        (__builtin_amdgcn_cvt_pk_fp8_f32(v, v, 0, false) & 0xff);
                }
            }
        return;
    }

    // ---------------- supp part (fp8 e4m3, BK=128 triangular) ----------------
    int tid = blockIdx.x;                      // 0..527
    int sw = (tid & 7) * 66 + (tid >> 3);      // XCD swizzle (528 = 8*66)
    int by = (int)((sqrtf(8.0f * (float)sw + 1.0f) - 1.0f) * 0.5f);
    while ((by + 1) * (by + 2) / 2 <= sw) ++by;
    while (by * (by + 1) / 2 > sw) --by;
    int bx = sw - by * (by + 1) / 2;           // bx <= by
    bool diag = (bx == by);
    int rb = by * 128, cb = bx * 128;
    if (t < 128) rt_s[t] = tag[rb + t];
    else         ct_s[t - 128] = tag[cb + t - 128];

    f32x4 acc[4][4] = {};
    for (int kk = 0; kk < D_N; kk += 128) {
        __syncthreads();
        stage_fp8_tile(e2f8, rb, kk, D_N, As8, t);
        stage_fp8_tile(e2f8, cb, kk, D_N, Bs8, t);
        __syncthreads();
        long a[4][4], b[4][4];
        #pragma unroll
        for (int mi = 0; mi < 4; ++mi) {
            int ar = wr * 64 + mi * 16 + l15;
            int br = wc * 64 + mi * 16 + l15;
            #pragma unroll
            for (int ks = 0; ks < 4; ++ks) {
                int off = (ks * 32 + g * 8) ^ (x7 << 4);
                a[mi][ks] = *(const long*)(As8 + ar * 128 + off);
                b[mi][ks] = *(const long*)(Bs8 + br * 128 + off);
            }
        }
        #pragma unroll
        for (int mi = 0; mi < 4; ++mi)
            #pragma unroll
            for (int ni = 0; ni < 4; ++ni)
                #pragma unroll
                for (int ks = 0; ks < 4; ++ks)
                    acc[mi][ni] = __builtin_amdgcn_mfma_f32_16x16x32_fp8_fp8(
                        a[mi][ks], b[ni][ks], acc[mi][ni], 0, 0, 0);
    }
    int ct[4];
    #pragma unroll
    for (int ni = 0; ni < 4; ++ni) ct[ni] = ct_s[wc * 64 + ni * 16 + l15];
    float cd[4] = {}, cn[4] = {};
    #pragma unroll
    for (int mi = 0; mi < 4; ++mi) {
        #pragma unroll
        for (int r = 0; r < 4; ++r) {
            int row = wr * 64 + mi * 16 + g * 4 + r;
            int rt = rt_s[row];
            float d = 0.f, n = 0.f;
            #pragma unroll
            for (int ni = 0; ni < 4; ++ni) {
                float v = __expf(TAU_F * acc[mi][ni][r]);
                float nv = (ct[ni] != rt) ? v : 0.f;
                d += v; n += nv;
                cd[ni] += v; cn[ni] += nv;
            }
            #pragma unroll
            for (int mm = 1; mm < 16; mm <<= 1) {
                d += __shfl_xor(d, mm);
                n += __shfl_xor(n, mm);
            }
            if (l15 == 0) {
                pden[bx * B_N + rb + row] = d;   // slot bx, plain store
                pnom[bx * B_N + rb + row] = n;
            }
        }
    }
    if (!diag) {
        #pragma unroll
        for (int ni = 0; ni < 4; ++ni) {
            float d = cd[ni], n = cn[ni];
            d += __shfl_xor(d, 16); d += __shfl_xor(d, 32);
            n += __shfl_xor(n, 16); n += __shfl_xor(n, 32);
            if (g == 0) {
                int col = wc * 64 + ni * 16 + l15;
                pden[by * B_N + cb + col] = d;   // slot by, plain store
                pnom[by * B_N + cb + col] = n;
            }
        }
    }
}

// ---------------------------------------------------------------------------
// aug: one 8-lane group per (j,item); BOTH operands fp8 (halves the dominant
// L2 traffic term — e2 re-reads — and cuts decode VALU vs bf16 shifts).
__global__ __launch_bounds__(256, 4) void aug_dots_kernel(
        const unsigned char* __restrict__ e2f8,
        const unsigned char* __restrict__ phif8,
        const int* __restrict__ neg_idx, float* __restrict__ sexp) {
    int gi = blockIdx.x * 32 + (threadIdx.x >> 3);
    int sub = threadIdx.x & 7;
    int j = gi / ITEMS_J;
    int idx = gi - j * ITEMS_J;
    int tgt = (idx == 0) ? j : neg_idx[(size_t)j * N_NEGS + idx - 1];
    const unsigned char* e = e2f8  + (size_t)j   * D_N + sub * 8;
    const unsigned char* p = phif8 + (size_t)tgt * D_N + sub * 8;

    uint2 pv[8], ev[8];
    #pragma unroll
    for (int k = 0; k < 8; ++k) {
        pv[k] = *(const uint2*)(p + k * 64);
        ev[k] = *(const uint2*)(e + k * 64);
    }
    float s0 = 0.f, s1 = 0.f;
    #pragma unroll
    for (int k = 0; k < 8; ++k) {
        f32x2 a0 = __builtin_amdgcn_cvt_pk_f32_fp8((int)pv[k].x, false);
        f32x2 a1 = __builtin_amdgcn_cvt_pk_f32_fp8((int)pv[k].x, true);
        f32x2 a2 = __builtin_amdgcn_cvt_pk_f32_fp8((int)pv[k].y, false);
        f32x2 a3 = __builtin_amdgcn_cvt_pk_f32_fp8((int)pv[k].y, true);
        f32x2 b0 = __builtin_amdgcn_cvt_pk_f32_fp8((int)ev[k].x, false);
        f32x2 b1 = __builtin_amdgcn_cvt_pk_f32_fp8((int)ev[k].x, true);
        f32x2 b2 = __builtin_amdgcn_cvt_pk_f32_fp8((int)ev[k].y, false);
        f32x2 b3 = __builtin_amdgcn_cvt_pk_f32_fp8((int)ev[k].y, true);
        s0 += b0.x * a0.x + b0.y * a0.y + b1.x * a1.x + b1.y * a1.y;
        s1 += b2.x * a2.x + b2.y * a2.y + b3.x * a3.x + b3.y * a3.y;
    }
    float s = s0 + s1;
    s += __shfl_xor(s, 1);
    s += __shfl_xor(s, 2);
    s += __shfl_xor(s, 4);
    if (sub == 0) sexp[(size_t)j * SEXP_LD + idx] = __expf(TAU_F * s);
}

// ---------------------------------------------------------------------------
// final1: 64 blocks; per j: reduce sexp row -> L_a, reduce 32 den/nom
// partial slots -> L_s; write per-block {La,Ls} partials (plain stores).
__global__ __launch_bounds__(256) void final1_kernel(
        const float* __restrict__ sexp, const float* __restrict__ pden,
        const float* __restrict__ pnom, const int* __restrict__ tag,
        float* __restrict__ stat) {
    __shared__ float wla[4], wls[4];
    int lane = threadIdx.x & 63, w = threadIdx.x >> 6;
    int j0 = blockIdx.x * 64;
    float la = 0.f, ls = 0.f;
    for (int jj = w; jj < 64; jj += 4) {
        int j = j0 + jj;
        float v0 = sexp[(size_t)j * SEXP_LD + lane];
        float v1 = (lane + 64 < ITEMS_J) ? sexp[(size_t)j * SEXP_LD + lane + 64] : 0.f;
        float pos = __shfl(v0, 0);
        float ns = ((lane >= 1) ? v0 : 0.f) + v1;
        float d = (lane < 32) ? pden[lane * B_N + j] : 0.f;
        float n = (lane < 32) ? pnom[lane * B_N + j] : 0.f;
        #pragma unroll
        for (int mm = 32; mm; mm >>= 1) {
            ns += __shfl_xor(ns, mm);
            d  += __shfl_xor(d, mm);
            n  += __shfl_xor(n, mm);
        }
        if (lane == 0) {
            float La = logf(pos / (EPS_F + pos + ns));
            if (La == La) la += La;
            float Ls = logf(n / (d + EPS_F));
            bool valid = (stat[S_HIST + tag[j]] < (float)B_N) && (Ls == Ls);
            if (valid) ls += Ls;
        }
    }
    if (lane == 0) { wla[w] = la; wls[w] = ls; }
    __syncthreads();
    if (threadIdx.x == 0) {
        stat[S_FIN + blockIdx.x * 2]     = wla[0] + wla[1] + wla[2] + wla[3];
        stat[S_FIN + blockIdx.x * 2 + 1] = wls[0] + wls[1] + wls[2] + wls[3];
    }
}

// ---------------------------------------------------------------------------
__global__ __launch_bounds__(256) void final2_kernel(
        const float* __restrict__ stat, float* __restrict__ out) {
    __shared__ float sred[4];
    int t = threadIdx.x;
    float w2 = block_sum256(t < 64 ? stat[S_W2P + t] : 0.f, sred);
    float la = block_sum256(t < 64 ? stat[S_FIN + 2 * t] : 0.f, sred);
    float ls = block_sum256(t < 64 ? stat[S_FIN + 2 * t + 1] : 0.f, sred);
    if (t == 0) {
        out[0] = stat[S_MSE] / (float)B_N;
        out[1] = REGW_F * (sqrtf(w2) + sqrtf(stat[S_B2]) +
                           sqrtf(stat[S_WH2]) + sqrtf(stat[S_BH2]));
        out[2] = -la / (float)B_N;
        out[3] = -ls / (float)B_N;
    }
}

// ---------------------------------------------------------------------------
extern "C" void kernel_launch(void* const* d_in, const int* in_sizes, int n_in,
                              void* d_out, int out_size, void* d_ws, size_t ws_size,
                              hipStream_t stream) {
    const float* e1       = (const float*)d_in[0];
    const float* e2       = (const float*)d_in[1];
    const float* y_pred   = (const float*)d_in[2];
    const float* y_target = (const float*)d_in[3];
    const float* W_e2     = (const float*)d_in[4];
    const float* b_e2     = (const float*)d_in[5];
    const float* W_head   = (const float*)d_in[6];
    const float* b_head   = (const float*)d_in[7];
    const float* lmbda    = (const float*)d_in[8];
    const int*   mix_idx  = (const int*)d_in[9];
    const int*   neg_idx  = (const int*)d_in[10];
    const int*   dtag     = (const int*)d_in[11];
    char* base = (char*)d_ws;
    float* out = (float*)d_out;
    unsigned char* phif8 = (unsigned char*)(base + PHIF8_B);
    unsigned char* e2f8  = (unsigned char*)(base + E2F8_B);
    ushort* wtb  = (ushort*)(base + WTB_B);
    ushort* augb = (ushort*)(base + AUGB_B);
    float*  sexp = (float*)(base + SEXP_B);
    float*  pden = (float*)(base + PDEN_B);
    float*  pnom = (float*)(base + PNOM_B);
    float*  stat = (float*)(base + STAT_B);

    prep_kernel<<<dim3(2115), dim3(256), 0, stream>>>(
        y_pred, y_target, W_e2, b_e2, W_head, b_head, e2, e1, lmbda, mix_idx,
        dtag, wtb, augb, e2f8, stat);
    gemm_kernel<<<dim3(SUPP_NB + 256), dim3(256), 0, stream>>>(
        e2f8, dtag, augb, wtb, b_e2, pden, pnom, phif8);
    aug_dots_kernel<<<dim3(B_N * ITEMS_J / 32), dim3(256), 0, stream>>>(
        e2f8, phif8, neg_idx, sexp);
    final1_kernel<<<dim3(64), dim3(256), 0, stream>>>(
        sexp, pden, pnom, dtag, stat);
    final2_kernel<<<dim3(1), dim3(256), 0, stream>>>(stat, out);
}

// Round 17
// 72.455 us; speedup vs baseline: 1.3968x; 1.1052x over previous
//
#include <hip/hip_runtime.h>
#include <hip/hip_bf16.h>
#include <math.h>

#define B_N 4096
#define D_N 512
#define N_NEGS 100
#define N_DOM 8
#define TAU_F 1e-4f
#define EPS_F 1e-6f
#define REGW_F 1e-4f
#define ITEMS_J 101
#define SEXP_LD 102
#define SUPP_NB 528

typedef __attribute__((ext_vector_type(8))) short bf16x8;
typedef __attribute__((ext_vector_type(4))) float f32x4;
typedef __attribute__((ext_vector_type(2))) float f32x2;

// ---- workspace layout (byte offsets). ~11.5 MB used, all plain-store init.
#define PHIF8_B 0u                      // fp8 phi [4096][512]        (2 MB)
#define E2F8_B  (2u << 20)              // fp8 e2  [4096][512]        (2 MB)
#define WTB_B   (4u << 20)              // bf16 W^T [512][512]        (0.5 MB)
#define AUGB_B  (WTB_B + (1u << 19))    // bf16 mixup(e1) [4096][512] (4 MB)
#define SEXP_B  (AUGB_B + (4u << 20))   // f32 [4096][102]            (1.7 MB)
#define PDEN_B  (SEXP_B + (2u << 20))   // f32 [32][4096] den partials (512 KB)
#define PNOM_B  (PDEN_B + (1u << 19))   // f32 [32][4096] nom partials (512 KB)
#define STAT_B  (PNOM_B + (1u << 19))   // stats floats
// stat region (float indices) — every slot plain-stored each call, no init
#define S_MSE  0
#define S_B2   1
#define S_WH2  2
#define S_BH2  3
#define S_HIST 8                        // 8 domain counts (as float)
#define S_W2P  16                       // 64 ||W||^2 partials (one per wtb tile)
#define S_FIN  144                      // 64 x {La, Ls} block partials

// ---------------------------------------------------------------------------
__device__ __forceinline__ ushort f2bf(float f) {
    union { __hip_bfloat16 h; ushort u; } v;
    v.h = __float2bfloat16(f);
    return v.u;
}

// global->LDS async staging (linear LDS dest, pre-swizzled global source so
// reads XOR-swizzle; T2/m201 pattern).
__device__ __forceinline__ void stage_bf16_tile(
        const ushort* __restrict__ g, int row0, int col0, int ldg,
        ushort* lds, int t) {
    int wid = t >> 6, lane = t & 63;
    #pragma unroll
    for (int i = 0; i < 4; ++i) {
        int p = i * 4096 + wid * 1024 + lane * 16;
        int row = p >> 7;
        int colb = (p & 127) ^ ((row & 7) << 4);
        const ushort* src = g + (size_t)(row0 + row) * ldg + col0 + (colb >> 1);
        ushort* dst = lds + (i * 4096 + wid * 1024) / 2;
        __builtin_amdgcn_global_load_lds(
            (const __attribute__((address_space(1))) unsigned int*)src,
            (__attribute__((address_space(3))) unsigned int*)dst, 16, 0, 0);
    }
}
// 64x64 bf16 variant (8 KB)
__device__ __forceinline__ void stage_bf16_tile64(
        const ushort* __restrict__ g, int row0, int col0, int ldg,
        ushort* lds, int t) {
    int wid = t >> 6, lane = t & 63;
    #pragma unroll
    for (int i = 0; i < 2; ++i) {
        int p = i * 4096 + wid * 1024 + lane * 16;
        int row = p >> 7;
        int colb = (p & 127) ^ ((row & 7) << 4);
        const ushort* src = g + (size_t)(row0 + row) * ldg + col0 + (colb >> 1);
        ushort* dst = lds + (i * 4096 + wid * 1024) / 2;
        __builtin_amdgcn_global_load_lds(
            (const __attribute__((address_space(1))) unsigned int*)src,
            (__attribute__((address_space(3))) unsigned int*)dst, 16, 0, 0);
    }
}
// 128x128 fp8 tile (16 KB): rows are 128 B -> identical byte arithmetic.
__device__ __forceinline__ void stage_fp8_tile(
        const unsigned char* __restrict__ g, int row0, int col0, int ldg,
        unsigned char* lds, int t) {
    int wid = t >> 6, lane = t & 63;
    #pragma unroll
    for (int i = 0; i < 4; ++i) {
        int p = i * 4096 + wid * 1024 + lane * 16;
        int row = p >> 7;
        int colb = (p & 127) ^ ((row & 7) << 4);
        const unsigned char* src = g + (size_t)(row0 + row) * ldg + col0 + colb;
        unsigned char* dst = lds + i * 4096 + wid * 1024;
        __builtin_amdgcn_global_load_lds(
            (const __attribute__((address_space(1))) unsigned int*)src,
            (__attribute__((address_space(3))) unsigned int*)dst, 16, 0, 0);
    }
}

// ---------------------------------------------------------------------------
__device__ __forceinline__ float block_sum256(float v, float* sred) {
    #pragma unroll
    for (int m = 32; m; m >>= 1) v += __shfl_xor(v, m, 64);
    int lane = threadIdx.x & 63, wid = threadIdx.x >> 6;
    __syncthreads();
    if (lane == 0) sred[wid] = v;
    __syncthreads();
    float s = 0.0f;
    if (threadIdx.x == 0) s = sred[0] + sred[1] + sred[2] + sred[3];
    return s;
}

// ---------------------------------------------------------------------------
// prep: all input-only work, one flat grid, NO atomics, inputs read ONCE.
//   x <  1024: e2 -> fp8 (single read)
//   x < 2048 : mixup(e1) -> bf16 augb
//   x < 2112 : wtb transpose tile + ||W||^2 partial (single read of W)
//   x == 2112: mse   x == 2113: small norms   x == 2114: histogram
__global__ __launch_bounds__(256) void prep_kernel(
        const float* __restrict__ y_pred, const float* __restrict__ y_target,
        const float* __restrict__ W_e2, const float* __restrict__ b_e2,
        const float* __restrict__ W_head, const float* __restrict__ b_head,
        const float* __restrict__ e2, const float* __restrict__ e1,
        const float* __restrict__ lmbda, const int* __restrict__ mix,
        const int* __restrict__ tag,
        ushort* __restrict__ wtb, ushort* __restrict__ augb,
        unsigned char* __restrict__ e2f8, float* __restrict__ stat) {
    int t = threadIdx.x, x = blockIdx.x;
    if (x < 1024) {                       // e2 -> fp8, one read
        int i = (x * 256 + t) * 8;
        f32x4 v0 = *(const f32x4*)(e2 + i);
        f32x4 v1 = *(const f32x4*)(e2 + i + 4);
        int w0 = 0, w1 = 0;
        w0 = __builtin_amdgcn_cvt_pk_fp8_f32(v0.x, v0.y, w0, false);
        w0 = __builtin_amdgcn_cvt_pk_fp8_f32(v0.z, v0.w, w0, true);
        w1 = __builtin_amdgcn_cvt_pk_fp8_f32(v1.x, v1.y, w1, false);
        w1 = __builtin_amdgcn_cvt_pk_fp8_f32(v1.z, v1.w, w1, true);
        *(int2*)(e2f8 + i) = make_int2(w0, w1);
        return;
    }
    if (x < 2048) {                       // mixup -> bf16 augb
        int i = ((x - 1024) * 256 + t) * 8;
        int row = i >> 9, col = i & 511;
        float lam = lmbda[row], oml = 1.0f - lam;
        const float* a = e1 + (size_t)row * D_N + col;
        const float* c = e1 + (size_t)mix[row] * D_N + col;
        f32x4 a0 = *(const f32x4*)a, a1 = *(const f32x4*)(a + 4);
        f32x4 c0 = *(const f32x4*)c, c1 = *(const f32x4*)(c + 4);
        bf16x8 o;
        o[0] = (short)f2bf(lam * a0.x + oml * c0.x);
        o[1] = (short)f2bf(lam * a0.y + oml * c0.y);
        o[2] = (short)f2bf(lam * a0.z + oml * c0.z);
        o[3] = (short)f2bf(lam * a0.w + oml * c0.w);
        o[4] = (short)f2bf(lam * a1.x + oml * c1.x);
        o[5] = (short)f2bf(lam * a1.y + oml * c1.y);
        o[6] = (short)f2bf(lam * a1.z + oml * c1.z);
        o[7] = (short)f2bf(lam * a1.w + oml * c1.w);
        *(bf16x8*)(augb + i) = o;
        return;
    }
    if (x < 2112) {                       // wtb tile + W2 partial, one read
        int xx = x - 2048;                // 0..63
        __shared__ float tile[64][65];
        __shared__ float sred[4];
        int k0 = (xx >> 3) * 64, n0 = (xx & 7) * 64;
        int r = t >> 4, c = (t & 15) * 4;
        float ss = 0.0f;
        #pragma unroll
        for (int i = 0; i < 4; ++i) {
            f32x4 v = *(const f32x4*)(W_e2 + (size_t)(k0 + r + i * 16) * D_N + n0 + c);
            tile[r + i * 16][c]     = v.x;
            tile[r + i * 16][c + 1] = v.y;
            tile[r + i * 16][c + 2] = v.z;
            tile[r + i * 16][c + 3] = v.w;
            ss += v.x * v.x + v.y * v.y + v.z * v.z + v.w * v.w;
        }
        __syncthreads();
        int nl = t >> 2, kq = (t & 3) * 16;
        bf16x8 o0, o1;
        #pragma unroll
        for (int q = 0; q < 8; ++q) o0[q] = (short)f2bf(tile[kq + q][nl]);
        #pragma unroll
        for (int q = 0; q < 8; ++q) o1[q] = (short)f2bf(tile[kq + 8 + q][nl]);
        ushort* dst = wtb + (size_t)(n0 + nl) * D_N + k0 + kq;
        *(bf16x8*)dst = o0;
        *(bf16x8*)(dst + 8) = o1;
        float s = block_sum256(ss, sred);
        if (t == 0) stat[S_W2P + xx] = s;
        return;
    }
    __shared__ float sred[4];
    if (x == 2112) {
        float s = 0.0f;
        for (int i = t; i < B_N; i += 256) {
            float d = y_pred[i] - y_target[i]; s += d * d;
        }
        s = block_sum256(s, sred);
        if (t == 0) stat[S_MSE] = s;
    } else if (x == 2113) {
        float v1 = b_e2[t], v2 = b_e2[t + 256];
        float s = block_sum256(v1 * v1 + v2 * v2, sred);
        if (t == 0) stat[S_B2] = s;
        v1 = W_head[t]; v2 = W_head[t + 256];
        s = block_sum256(v1 * v1 + v2 * v2, sred);
        if (t == 0) {
            stat[S_WH2] = s;
            stat[S_BH2] = b_head[0] * b_head[0];
        }
    } else if (x == 2114) {
        __shared__ int h[N_DOM];
        if (t < N_DOM) h[t] = 0;
        __syncthreads();
        for (int i = t; i < B_N; i += 256) atomicAdd(&h[tag[i]], 1);
        __syncthreads();
        if (t < N_DOM) stat[S_HIST + t] = (float)h[t];
    }
}

// ---------------------------------------------------------------------------
// gemm: HOMOGENEOUS fusion of supp (blocks 0..527, fp8 BK=128 triangular
// Gram) and phi (blocks 528..783, bf16 64x128 GEMM -> fp8 out).
__global__ __launch_bounds__(256) void gemm_kernel(
        const unsigned char* __restrict__ e2f8, const int* __restrict__ tag,
        const ushort* __restrict__ augb, const ushort* __restrict__ wtb,
        const float* __restrict__ bvec,
        float* __restrict__ pden, float* __restrict__ pnom,
        unsigned char* __restrict__ phif8) {
    __shared__ unsigned char As8[128 * 128];
    __shared__ unsigned char Bs8[128 * 128];
    __shared__ int rt_s[128], ct_s[128];
    int t = threadIdx.x;
    int lane = t & 63, wid = t >> 6;
    int l15 = lane & 15, g = lane >> 4, x7 = l15 & 7;
    int wr = wid >> 1, wc = wid & 1;

    if (blockIdx.x >= SUPP_NB) {
        // ---------------- phi part (bf16, 64x128 tile) ----------------
        int bid = blockIdx.x - SUPP_NB;            // 0..255
        int rb = (bid >> 2) * 64, cb = (bid & 3) * 128;
        ushort* As = (ushort*)As8;
        ushort* Bs = (ushort*)Bs8;
        f32x4 acc[2][4] = {};
        for (int kk = 0; kk < D_N; kk += 64) {
            __syncthreads();
            stage_bf16_tile64(augb, rb, kk, D_N, As, t);
            stage_bf16_tile  (wtb,  cb, kk, D_N, Bs, t);
            __syncthreads();
            bf16x8 a[2][2], b[4][2];
            #pragma unroll
            for (int mi = 0; mi < 2; ++mi)
                #pragma unroll
                for (int ks = 0; ks < 2; ++ks) {
                    int ar = wr * 32 + mi * 16 + l15;
                    a[mi][ks] = *(const bf16x8*)((const char*)As +
                        ar * 128 + (((ks << 2) | g) ^ x7) * 16);
                }
            #pragma unroll
            for (int ni = 0; ni < 4; ++ni)
                #pragma unroll
                for (int ks = 0; ks < 2; ++ks) {
                    int br = wc * 64 + ni * 16 + l15;
                    b[ni][ks] = *(const bf16x8*)((const char*)Bs +
                        br * 128 + (((ks << 2) | g) ^ x7) * 16);
                }
            #pragma unroll
            for (int mi = 0; mi < 2; ++mi)
                #pragma unroll
                for (int ni = 0; ni < 4; ++ni)
                    #pragma unroll
                    for (int ks = 0; ks < 2; ++ks)
                        acc[mi][ni] = __builtin_amdgcn_mfma_f32_16x16x32_bf16(
                            a[mi][ks], b[ni][ks], acc[mi][ni], 0, 0, 0);
        }
        float bb[4];
        #pragma unroll
        for (int ni = 0; ni < 4; ++ni) bb[ni] = bvec[cb + wc * 64 + ni * 16 + l15];
        #pragma unroll
        for (int mi = 0; mi < 2; ++mi)
            #pragma unroll
            for (int r = 0; r < 4; ++r) {
                int row = rb + wr * 32 + mi * 16 + g * 4 + r;
                #pragma unroll
                for (int ni = 0; ni < 4; ++ni) {
                    int col = cb + wc * 64 + ni * 16 + l15;
                    float v = acc[mi][ni][r] + bb[ni];
                    phif8[(size_t)row * D_N + col] = (unsigned char)
                        (__builtin_amdgcn_cvt_pk_fp8_f32(v, v, 0, false) & 0xff);
                }
            }
        return;
    }

    // ---------------- supp part (fp8 e4m3, BK=128 triangular) ----------------
    int tid = blockIdx.x;                      // 0..527
    int sw = (tid & 7) * 66 + (tid >> 3);      // XCD swizzle (528 = 8*66)
    int by = (int)((sqrtf(8.0f * (float)sw + 1.0f) - 1.0f) * 0.5f);
    while ((by + 1) * (by + 2) / 2 <= sw) ++by;
    while (by * (by + 1) / 2 > sw) --by;
    int bx = sw - by * (by + 1) / 2;           // bx <= by
    bool diag = (bx == by);
    int rb = by * 128, cb = bx * 128;
    if (t < 128) rt_s[t] = tag[rb + t];
    else         ct_s[t - 128] = tag[cb + t - 128];

    f32x4 acc[4][4] = {};
    for (int kk = 0; kk < D_N; kk += 128) {
        __syncthreads();
        stage_fp8_tile(e2f8, rb, kk, D_N, As8, t);
        stage_fp8_tile(e2f8, cb, kk, D_N, Bs8, t);
        __syncthreads();
        long a[4][4], b[4][4];
        #pragma unroll
        for (int mi = 0; mi < 4; ++mi) {
            int ar = wr * 64 + mi * 16 + l15;
            int br = wc * 64 + mi * 16 + l15;
            #pragma unroll
            for (int ks = 0; ks < 4; ++ks) {
                int off = (ks * 32 + g * 8) ^ (x7 << 4);
                a[mi][ks] = *(const long*)(As8 + ar * 128 + off);
                b[mi][ks] = *(const long*)(Bs8 + br * 128 + off);
            }
        }
        #pragma unroll
        for (int mi = 0; mi < 4; ++mi)
            #pragma unroll
            for (int ni = 0; ni < 4; ++ni)
                #pragma unroll
                for (int ks = 0; ks < 4; ++ks)
                    acc[mi][ni] = __builtin_amdgcn_mfma_f32_16x16x32_fp8_fp8(
                        a[mi][ks], b[ni][ks], acc[mi][ni], 0, 0, 0);
    }
    int ct[4];
    #pragma unroll
    for (int ni = 0; ni < 4; ++ni) ct[ni] = ct_s[wc * 64 + ni * 16 + l15];
    float cd[4] = {}, cn[4] = {};
    #pragma unroll
    for (int mi = 0; mi < 4; ++mi) {
        #pragma unroll
        for (int r = 0; r < 4; ++r) {
            int row = wr * 64 + mi * 16 + g * 4 + r;
            int rt = rt_s[row];
            float d = 0.f, n = 0.f;
            #pragma unroll
            for (int ni = 0; ni < 4; ++ni) {
                float v = __expf(TAU_F * acc[mi][ni][r]);
                float nv = (ct[ni] != rt) ? v : 0.f;
                d += v; n += nv;
                cd[ni] += v; cn[ni] += nv;
            }
            #pragma unroll
            for (int mm = 1; mm < 16; mm <<= 1) {
                d += __shfl_xor(d, mm);
                n += __shfl_xor(n, mm);
            }
            if (l15 == 0) {
                pden[bx * B_N + rb + row] = d;   // slot bx, plain store
                pnom[bx * B_N + rb + row] = n;
            }
        }
    }
    if (!diag) {
        #pragma unroll
        for (int ni = 0; ni < 4; ++ni) {
            float d = cd[ni], n = cn[ni];
            d += __shfl_xor(d, 16); d += __shfl_xor(d, 32);
            n += __shfl_xor(n, 16); n += __shfl_xor(n, 32);
            if (g == 0) {
                int col = wc * 64 + ni * 16 + l15;
                pden[by * B_N + cb + col] = d;   // slot by, plain store
                pnom[by * B_N + cb + col] = n;
            }
        }
    }
}

// ---------------------------------------------------------------------------
// aug: one 8-lane group per (j,item), ALL loads 16B dwordx4 — 8 VMEM
// instructions/thread instead of 16. aug is VMEM-ISSUE-RATE bound (53M loads
// / 1024 SIMDs / 2.4GHz = 21.5us floor == measured; rounds 11/16 nulls both
// consistent: neither changed the instruction count). Halving instrs -> ~11us.
// Lane sub covers bytes [sub*16 + k*128, +16) — 8 lanes = 128 contiguous
// bytes per step, fully coalesced; dot product is position-aligned.
__global__ __launch_bounds__(256, 4) void aug_dots_kernel(
        const unsigned char* __restrict__ e2f8,
        const unsigned char* __restrict__ phif8,
        const int* __restrict__ neg_idx, float* __restrict__ sexp) {
    int gi = blockIdx.x * 32 + (threadIdx.x >> 3);
    int sub = threadIdx.x & 7;
    int j = gi / ITEMS_J;
    int idx = gi - j * ITEMS_J;
    int tgt = (idx == 0) ? j : neg_idx[(size_t)j * N_NEGS + idx - 1];
    const unsigned char* e = e2f8  + (size_t)j   * D_N + sub * 16;
    const unsigned char* p = phif8 + (size_t)tgt * D_N + sub * 16;

    uint4 pv[4], ev[4];
    #pragma unroll
    for (int k = 0; k < 4; ++k) {
        pv[k] = *(const uint4*)(p + k * 128);
        ev[k] = *(const uint4*)(e + k * 128);
    }
    float s0 = 0.f, s1 = 0.f;
    #pragma unroll
    for (int k = 0; k < 4; ++k) {
        uint pw[4] = {pv[k].x, pv[k].y, pv[k].z, pv[k].w};
        uint ew[4] = {ev[k].x, ev[k].y, ev[k].z, ev[k].w};
        #pragma unroll
        for (int w = 0; w < 4; ++w) {
            f32x2 a0 = __builtin_amdgcn_cvt_pk_f32_fp8((int)pw[w], false);
            f32x2 a1 = __builtin_amdgcn_cvt_pk_f32_fp8((int)pw[w], true);
            f32x2 b0 = __builtin_amdgcn_cvt_pk_f32_fp8((int)ew[w], false);
            f32x2 b1 = __builtin_amdgcn_cvt_pk_f32_fp8((int)ew[w], true);
            s0 += b0.x * a0.x + b0.y * a0.y;
            s1 += b1.x * a1.x + b1.y * a1.y;
        }
    }
    float s = s0 + s1;
    s += __shfl_xor(s, 1);
    s += __shfl_xor(s, 2);
    s += __shfl_xor(s, 4);
    if (sub == 0) sexp[(size_t)j * SEXP_LD + idx] = __expf(TAU_F * s);
}

// ---------------------------------------------------------------------------
// final1: 64 blocks; per j: reduce sexp row -> L_a, reduce 32 den/nom
// partial slots -> L_s; write per-block {La,Ls} partials (plain stores).
__global__ __launch_bounds__(256) void final1_kernel(
        const float* __restrict__ sexp, const float* __restrict__ pden,
        const float* __restrict__ pnom, const int* __restrict__ tag,
        float* __restrict__ stat) {
    __shared__ float wla[4], wls[4];
    int lane = threadIdx.x & 63, w = threadIdx.x >> 6;
    int j0 = blockIdx.x * 64;
    float la = 0.f, ls = 0.f;
    for (int jj = w; jj < 64; jj += 4) {
        int j = j0 + jj;
        float v0 = sexp[(size_t)j * SEXP_LD + lane];
        float v1 = (lane + 64 < ITEMS_J) ? sexp[(size_t)j * SEXP_LD + lane + 64] : 0.f;
        float pos = __shfl(v0, 0);
        float ns = ((lane >= 1) ? v0 : 0.f) + v1;
        float d = (lane < 32) ? pden[lane * B_N + j] : 0.f;
        float n = (lane < 32) ? pnom[lane * B_N + j] : 0.f;
        #pragma unroll
        for (int mm = 32; mm; mm >>= 1) {
            ns += __shfl_xor(ns, mm);
            d  += __shfl_xor(d, mm);
            n  += __shfl_xor(n, mm);
        }
        if (lane == 0) {
            float La = logf(pos / (EPS_F + pos + ns));
            if (La == La) la += La;
            float Ls = logf(n / (d + EPS_F));
            bool valid = (stat[S_HIST + tag[j]] < (float)B_N) && (Ls == Ls);
            if (valid) ls += Ls;
        }
    }
    if (lane == 0) { wla[w] = la; wls[w] = ls; }
    __syncthreads();
    if (threadIdx.x == 0) {
        stat[S_FIN + blockIdx.x * 2]     = wla[0] + wla[1] + wla[2] + wla[3];
        stat[S_FIN + blockIdx.x * 2 + 1] = wls[0] + wls[1] + wls[2] + wls[3];
    }
}

// ---------------------------------------------------------------------------
__global__ __launch_bounds__(256) void final2_kernel(
        const float* __restrict__ stat, float* __restrict__ out) {
    __shared__ float sred[4];
    int t = threadIdx.x;
    float w2 = block_sum256(t < 64 ? stat[S_W2P + t] : 0.f, sred);
    float la = block_sum256(t < 64 ? stat[S_FIN + 2 * t] : 0.f, sred);
    float ls = block_sum256(t < 64 ? stat[S_FIN + 2 * t + 1] : 0.f, sred);
    if (t == 0) {
        out[0] = stat[S_MSE] / (float)B_N;
        out[1] = REGW_F * (sqrtf(w2) + sqrtf(stat[S_B2]) +
                           sqrtf(stat[S_WH2]) + sqrtf(stat[S_BH2]));
        out[2] = -la / (float)B_N;
        out[3] = -ls / (float)B_N;
    }
}

// ---------------------------------------------------------------------------
extern "C" void kernel_launch(void* const* d_in, const int* in_sizes, int n_in,
                              void* d_out, int out_size, void* d_ws, size_t ws_size,
                              hipStream_t stream) {
    const float* e1       = (const float*)d_in[0];
    const float* e2       = (const float*)d_in[1];
    const float* y_pred   = (const float*)d_in[2];
    const float* y_target = (const float*)d_in[3];
    const float* W_e2     = (const float*)d_in[4];
    const float* b_e2     = (const float*)d_in[5];
    const float* W_head   = (const float*)d_in[6];
    const float* b_head   = (const float*)d_in[7];
    const float* lmbda    = (const float*)d_in[8];
    const int*   mix_idx  = (const int*)d_in[9];
    const int*   neg_idx  = (const int*)d_in[10];
    const int*   dtag     = (const int*)d_in[11];
    char* base = (char*)d_ws;
    float* out = (float*)d_out;
    unsigned char* phif8 = (unsigned char*)(base + PHIF8_B);
    unsigned char* e2f8  = (unsigned char*)(base + E2F8_B);
    ushort* wtb  = (ushort*)(base + WTB_B);
    ushort* augb = (ushort*)(base + AUGB_B);
    float*  sexp = (float*)(base + SEXP_B);
    float*  pden = (float*)(base + PDEN_B);
    float*  pnom = (float*)(base + PNOM_B);
    float*  stat = (float*)(base + STAT_B);

    prep_kernel<<<dim3(2115), dim3(256), 0, stream>>>(
        y_pred, y_target, W_e2, b_e2, W_head, b_head, e2, e1, lmbda, mix_idx,
        dtag, wtb, augb, e2f8, stat);
    gemm_kernel<<<dim3(SUPP_NB + 256), dim3(256), 0, stream>>>(
        e2f8, dtag, augb, wtb, b_e2, pden, pnom, phif8);
    aug_dots_kernel<<<dim3(B_N * ITEMS_J / 32), dim3(256), 0, stream>>>(
        e2f8, phif8, neg_idx, sexp);
    final1_kernel<<<dim3(64), dim3(256), 0, stream>>>(
        sexp, pden, pnom, dtag, sexp ? stat : stat);
    final2_kernel<<<dim3(1), dim3(256), 0, stream>>>(stat, out);
}

// Round 18
// 71.529 us; speedup vs baseline: 1.4149x; 1.0130x over previous
//
#include <hip/hip_runtime.h>
#include <hip/hip_bf16.h>
#include <math.h>

#define B_N 4096
#define D_N 512
#define N_NEGS 100
#define N_DOM 8
#define TAU_F 1e-4f
#define EPS_F 1e-6f
#define REGW_F 1e-4f
#define ITEMS_J 101
#define SEXP_LD 102
#define SUPP_NB 528
#define NQUAD 26                        // ceil(101/4) quads per j

typedef __attribute__((ext_vector_type(8))) short bf16x8;
typedef __attribute__((ext_vector_type(4))) float f32x4;
typedef __attribute__((ext_vector_type(2))) float f32x2;

// ---- workspace layout (byte offsets). ~11.5 MB used, all plain-store init.
#define PHIF8_B 0u                      // fp8 phi [4096][512]        (2 MB)
#define E2F8_B  (2u << 20)              // fp8 e2  [4096][512]        (2 MB)
#define WTB_B   (4u << 20)              // bf16 W^T [512][512]        (0.5 MB)
#define AUGB_B  (WTB_B + (1u << 19))    // bf16 mixup(e1) [4096][512] (4 MB)
#define SEXP_B  (AUGB_B + (4u << 20))   // f32 [4096][102]            (1.7 MB)
#define PDEN_B  (SEXP_B + (2u << 20))   // f32 [32][4096] den partials (512 KB)
#define PNOM_B  (PDEN_B + (1u << 19))   // f32 [32][4096] nom partials (512 KB)
#define STAT_B  (PNOM_B + (1u << 19))   // stats floats
// stat region (float indices) — every slot plain-stored each call, no init
#define S_MSE  0
#define S_B2   1
#define S_WH2  2
#define S_BH2  3
#define S_HIST 8                        // 8 domain counts (as float)
#define S_W2P  16                       // 64 ||W||^2 partials (one per wtb tile)
#define S_FIN  144                      // 64 x {La, Ls} block partials

// ---------------------------------------------------------------------------
__device__ __forceinline__ ushort f2bf(float f) {
    union { __hip_bfloat16 h; ushort u; } v;
    v.h = __float2bfloat16(f);
    return v.u;
}

// global->LDS async staging (linear LDS dest, pre-swizzled global source so
// reads XOR-swizzle; T2/m201 pattern).
__device__ __forceinline__ void stage_bf16_tile(
        const ushort* __restrict__ g, int row0, int col0, int ldg,
        ushort* lds, int t) {
    int wid = t >> 6, lane = t & 63;
    #pragma unroll
    for (int i = 0; i < 4; ++i) {
        int p = i * 4096 + wid * 1024 + lane * 16;
        int row = p >> 7;
        int colb = (p & 127) ^ ((row & 7) << 4);
        const ushort* src = g + (size_t)(row0 + row) * ldg + col0 + (colb >> 1);
        ushort* dst = lds + (i * 4096 + wid * 1024) / 2;
        __builtin_amdgcn_global_load_lds(
            (const __attribute__((address_space(1))) unsigned int*)src,
            (__attribute__((address_space(3))) unsigned int*)dst, 16, 0, 0);
    }
}
// 64x64 bf16 variant (8 KB)
__device__ __forceinline__ void stage_bf16_tile64(
        const ushort* __restrict__ g, int row0, int col0, int ldg,
        ushort* lds, int t) {
    int wid = t >> 6, lane = t & 63;
    #pragma unroll
    for (int i = 0; i < 2; ++i) {
        int p = i * 4096 + wid * 1024 + lane * 16;
        int row = p >> 7;
        int colb = (p & 127) ^ ((row & 7) << 4);
        const ushort* src = g + (size_t)(row0 + row) * ldg + col0 + (colb >> 1);
        ushort* dst = lds + (i * 4096 + wid * 1024) / 2;
        __builtin_amdgcn_global_load_lds(
            (const __attribute__((address_space(1))) unsigned int*)src,
            (__attribute__((address_space(3))) unsigned int*)dst, 16, 0, 0);
    }
}
// 128x128 fp8 tile (16 KB): rows are 128 B -> identical byte arithmetic.
__device__ __forceinline__ void stage_fp8_tile(
        const unsigned char* __restrict__ g, int row0, int col0, int ldg,
        unsigned char* lds, int t) {
    int wid = t >> 6, lane = t & 63;
    #pragma unroll
    for (int i = 0; i < 4; ++i) {
        int p = i * 4096 + wid * 1024 + lane * 16;
        int row = p >> 7;
        int colb = (p & 127) ^ ((row & 7) << 4);
        const unsigned char* src = g + (size_t)(row0 + row) * ldg + col0 + colb;
        unsigned char* dst = lds + i * 4096 + wid * 1024;
        __builtin_amdgcn_global_load_lds(
            (const __attribute__((address_space(1))) unsigned int*)src,
            (__attribute__((address_space(3))) unsigned int*)dst, 16, 0, 0);
    }
}

// ---------------------------------------------------------------------------
__device__ __forceinline__ float block_sum256(float v, float* sred) {
    #pragma unroll
    for (int m = 32; m; m >>= 1) v += __shfl_xor(v, m, 64);
    int lane = threadIdx.x & 63, wid = threadIdx.x >> 6;
    __syncthreads();
    if (lane == 0) sred[wid] = v;
    __syncthreads();
    float s = 0.0f;
    if (threadIdx.x == 0) s = sred[0] + sred[1] + sred[2] + sred[3];
    return s;
}

// ---------------------------------------------------------------------------
// prep: all input-only work, one flat grid, NO atomics, inputs read ONCE.
__global__ __launch_bounds__(256) void prep_kernel(
        const float* __restrict__ y_pred, const float* __restrict__ y_target,
        const float* __restrict__ W_e2, const float* __restrict__ b_e2,
        const float* __restrict__ W_head, const float* __restrict__ b_head,
        const float* __restrict__ e2, const float* __restrict__ e1,
        const float* __restrict__ lmbda, const int* __restrict__ mix,
        const int* __restrict__ tag,
        ushort* __restrict__ wtb, ushort* __restrict__ augb,
        unsigned char* __restrict__ e2f8, float* __restrict__ stat) {
    int t = threadIdx.x, x = blockIdx.x;
    if (x < 1024) {                       // e2 -> fp8, one read
        int i = (x * 256 + t) * 8;
        f32x4 v0 = *(const f32x4*)(e2 + i);
        f32x4 v1 = *(const f32x4*)(e2 + i + 4);
        int w0 = 0, w1 = 0;
        w0 = __builtin_amdgcn_cvt_pk_fp8_f32(v0.x, v0.y, w0, false);
        w0 = __builtin_amdgcn_cvt_pk_fp8_f32(v0.z, v0.w, w0, true);
        w1 = __builtin_amdgcn_cvt_pk_fp8_f32(v1.x, v1.y, w1, false);
        w1 = __builtin_amdgcn_cvt_pk_fp8_f32(v1.z, v1.w, w1, true);
        *(int2*)(e2f8 + i) = make_int2(w0, w1);
        return;
    }
    if (x < 2048) {                       // mixup -> bf16 augb
        int i = ((x - 1024) * 256 + t) * 8;
        int row = i >> 9, col = i & 511;
        float lam = lmbda[row], oml = 1.0f - lam;
        const float* a = e1 + (size_t)row * D_N + col;
        const float* c = e1 + (size_t)mix[row] * D_N + col;
        f32x4 a0 = *(const f32x4*)a, a1 = *(const f32x4*)(a + 4);
        f32x4 c0 = *(const f32x4*)c, c1 = *(const f32x4*)(c + 4);
        bf16x8 o;
        o[0] = (short)f2bf(lam * a0.x + oml * c0.x);
        o[1] = (short)f2bf(lam * a0.y + oml * c0.y);
        o[2] = (short)f2bf(lam * a0.z + oml * c0.z);
        o[3] = (short)f2bf(lam * a0.w + oml * c0.w);
        o[4] = (short)f2bf(lam * a1.x + oml * c1.x);
        o[5] = (short)f2bf(lam * a1.y + oml * c1.y);
        o[6] = (short)f2bf(lam * a1.z + oml * c1.z);
        o[7] = (short)f2bf(lam * a1.w + oml * c1.w);
        *(bf16x8*)(augb + i) = o;
        return;
    }
    if (x < 2112) {                       // wtb tile + W2 partial, one read
        int xx = x - 2048;                // 0..63
        __shared__ float tile[64][65];
        __shared__ float sred[4];
        int k0 = (xx >> 3) * 64, n0 = (xx & 7) * 64;
        int r = t >> 4, c = (t & 15) * 4;
        float ss = 0.0f;
        #pragma unroll
        for (int i = 0; i < 4; ++i) {
            f32x4 v = *(const f32x4*)(W_e2 + (size_t)(k0 + r + i * 16) * D_N + n0 + c);
            tile[r + i * 16][c]     = v.x;
            tile[r + i * 16][c + 1] = v.y;
            tile[r + i * 16][c + 2] = v.z;
            tile[r + i * 16][c + 3] = v.w;
            ss += v.x * v.x + v.y * v.y + v.z * v.z + v.w * v.w;
        }
        __syncthreads();
        int nl = t >> 2, kq = (t & 3) * 16;
        bf16x8 o0, o1;
        #pragma unroll
        for (int q = 0; q < 8; ++q) o0[q] = (short)f2bf(tile[kq + q][nl]);
        #pragma unroll
        for (int q = 0; q < 8; ++q) o1[q] = (short)f2bf(tile[kq + 8 + q][nl]);
        ushort* dst = wtb + (size_t)(n0 + nl) * D_N + k0 + kq;
        *(bf16x8*)dst = o0;
        *(bf16x8*)(dst + 8) = o1;
        float s = block_sum256(ss, sred);
        if (t == 0) stat[S_W2P + xx] = s;
        return;
    }
    __shared__ float sred[4];
    if (x == 2112) {
        float s = 0.0f;
        for (int i = t; i < B_N; i += 256) {
            float d = y_pred[i] - y_target[i]; s += d * d;
        }
        s = block_sum256(s, sred);
        if (t == 0) stat[S_MSE] = s;
    } else if (x == 2113) {
        float v1 = b_e2[t], v2 = b_e2[t + 256];
        float s = block_sum256(v1 * v1 + v2 * v2, sred);
        if (t == 0) stat[S_B2] = s;
        v1 = W_head[t]; v2 = W_head[t + 256];
        s = block_sum256(v1 * v1 + v2 * v2, sred);
        if (t == 0) {
            stat[S_WH2] = s;
            stat[S_BH2] = b_head[0] * b_head[0];
        }
    } else if (x == 2114) {
        __shared__ int h[N_DOM];
        if (t < N_DOM) h[t] = 0;
        __syncthreads();
        for (int i = t; i < B_N; i += 256) atomicAdd(&h[tag[i]], 1);
        __syncthreads();
        if (t < N_DOM) stat[S_HIST + t] = (float)h[t];
    }
}

// ---------------------------------------------------------------------------
// gemm: HOMOGENEOUS fusion of supp (blocks 0..527, fp8 BK=128 triangular
// Gram) and phi (blocks 528..783, bf16 64x128 GEMM -> fp8 out).
__global__ __launch_bounds__(256) void gemm_kernel(
        const unsigned char* __restrict__ e2f8, const int* __restrict__ tag,
        const ushort* __restrict__ augb, const ushort* __restrict__ wtb,
        const float* __restrict__ bvec,
        float* __restrict__ pden, float* __restrict__ pnom,
        unsigned char* __restrict__ phif8) {
    __shared__ unsigned char As8[128 * 128];
    __shared__ unsigned char Bs8[128 * 128];
    __shared__ int rt_s[128], ct_s[128];
    int t = threadIdx.x;
    int lane = t & 63, wid = t >> 6;
    int l15 = lane & 15, g = lane >> 4, x7 = l15 & 7;
    int wr = wid >> 1, wc = wid & 1;

    if (blockIdx.x >= SUPP_NB) {
        // ---------------- phi part (bf16, 64x128 tile) ----------------
        int bid = blockIdx.x - SUPP_NB;            // 0..255
        int rb = (bid >> 2) * 64, cb = (bid & 3) * 128;
        ushort* As = (ushort*)As8;
        ushort* Bs = (ushort*)Bs8;
        f32x4 acc[2][4] = {};
        for (int kk = 0; kk < D_N; kk += 64) {
            __syncthreads();
            stage_bf16_tile64(augb, rb, kk, D_N, As, t);
            stage_bf16_tile  (wtb,  cb, kk, D_N, Bs, t);
            __syncthreads();
            bf16x8 a[2][2], b[4][2];
            #pragma unroll
            for (int mi = 0; mi < 2; ++mi)
                #pragma unroll
                for (int ks = 0; ks < 2; ++ks) {
                    int ar = wr * 32 + mi * 16 + l15;
                    a[mi][ks] = *(const bf16x8*)((const char*)As +
                        ar * 128 + (((ks << 2) | g) ^ x7) * 16);
                }
            #pragma unroll
            for (int ni = 0; ni < 4; ++ni)
                #pragma unroll
                for (int ks = 0; ks < 2; ++ks) {
                    int br = wc * 64 + ni * 16 + l15;
                    b[ni][ks] = *(const bf16x8*)((const char*)Bs +
                        br * 128 + (((ks << 2) | g) ^ x7) * 16);
                }
            #pragma unroll
            for (int mi = 0; mi < 2; ++mi)
                #pragma unroll
                for (int ni = 0; ni < 4; ++ni)
                    #pragma unroll
                    for (int ks = 0; ks < 2; ++ks)
                        acc[mi][ni] = __builtin_amdgcn_mfma_f32_16x16x32_bf16(
                            a[mi][ks], b[ni][ks], acc[mi][ni], 0, 0, 0);
        }
        float bb[4];
        #pragma unroll
        for (int ni = 0; ni < 4; ++ni) bb[ni] = bvec[cb + wc * 64 + ni * 16 + l15];
        #pragma unroll
        for (int mi = 0; mi < 2; ++mi)
            #pragma unroll
            for (int r = 0; r < 4; ++r) {
                int row = rb + wr * 32 + mi * 16 + g * 4 + r;
                #pragma unroll
                for (int ni = 0; ni < 4; ++ni) {
                    int col = cb + wc * 64 + ni * 16 + l15;
                    float v = acc[mi][ni][r] + bb[ni];
                    phif8[(size_t)row * D_N + col] = (unsigned char)
                        (__builtin_amdgcn_cvt_pk_fp8_f32(v, v, 0, false) & 0xff);
                }
            }
        return;
    }

    // ---------------- supp part (fp8 e4m3, BK=128 triangular) ----------------
    int tid = blockIdx.x;                      // 0..527
    int sw = (tid & 7) * 66 + (tid >> 3);      // XCD swizzle (528 = 8*66)
    int by = (int)((sqrtf(8.0f * (float)sw + 1.0f) - 1.0f) * 0.5f);
    while ((by + 1) * (by + 2) / 2 <= sw) ++by;
    while (by * (by + 1) / 2 > sw) --by;
    int bx = sw - by * (by + 1) / 2;           // bx <= by
    bool diag = (bx == by);
    int rb = by * 128, cb = bx * 128;
    if (t < 128) rt_s[t] = tag[rb + t];
    else         ct_s[t - 128] = tag[cb + t - 128];

    f32x4 acc[4][4] = {};
    for (int kk = 0; kk < D_N; kk += 128) {
        __syncthreads();
        stage_fp8_tile(e2f8, rb, kk, D_N, As8, t);
        stage_fp8_tile(e2f8, cb, kk, D_N, Bs8, t);
        __syncthreads();
        long a[4][4], b[4][4];
        #pragma unroll
        for (int mi = 0; mi < 4; ++mi) {
            int ar = wr * 64 + mi * 16 + l15;
            int br = wc * 64 + mi * 16 + l15;
            #pragma unroll
            for (int ks = 0; ks < 4; ++ks) {
                int off = (ks * 32 + g * 8) ^ (x7 << 4);
                a[mi][ks] = *(const long*)(As8 + ar * 128 + off);
                b[mi][ks] = *(const long*)(Bs8 + br * 128 + off);
            }
        }
        #pragma unroll
        for (int mi = 0; mi < 4; ++mi)
            #pragma unroll
            for (int ni = 0; ni < 4; ++ni)
                #pragma unroll
                for (int ks = 0; ks < 4; ++ks)
                    acc[mi][ni] = __builtin_amdgcn_mfma_f32_16x16x32_fp8_fp8(
                        a[mi][ks], b[ni][ks], acc[mi][ni], 0, 0, 0);
    }
    int ct[4];
    #pragma unroll
    for (int ni = 0; ni < 4; ++ni) ct[ni] = ct_s[wc * 64 + ni * 16 + l15];
    float cd[4] = {}, cn[4] = {};
    #pragma unroll
    for (int mi = 0; mi < 4; ++mi) {
        #pragma unroll
        for (int r = 0; r < 4; ++r) {
            int row = wr * 64 + mi * 16 + g * 4 + r;
            int rt = rt_s[row];
            float d = 0.f, n = 0.f;
            #pragma unroll
            for (int ni = 0; ni < 4; ++ni) {
                float v = __expf(TAU_F * acc[mi][ni][r]);
                float nv = (ct[ni] != rt) ? v : 0.f;
                d += v; n += nv;
                cd[ni] += v; cn[ni] += nv;
            }
            #pragma unroll
            for (int mm = 1; mm < 16; mm <<= 1) {
                d += __shfl_xor(d, mm);
                n += __shfl_xor(n, mm);
            }
            if (l15 == 0) {
                pden[bx * B_N + rb + row] = d;   // slot bx, plain store
                pnom[bx * B_N + rb + row] = n;
            }
        }
    }
    if (!diag) {
        #pragma unroll
        for (int ni = 0; ni < 4; ++ni) {
            float d = cd[ni], n = cn[ni];
            d += __shfl_xor(d, 16); d += __shfl_xor(d, 32);
            n += __shfl_xor(n, 16); n += __shfl_xor(n, 32);
            if (g == 0) {
                int col = wc * 64 + ni * 16 + l15;
                pden[by * B_N + cb + col] = d;   // slot by, plain store
                pnom[by * B_N + cb + col] = n;
            }
        }
    }
}

// ---------------------------------------------------------------------------
// aug: one 8-lane group per (j, item-QUAD). e2 row loaded+decoded ONCE per
// quad (4 dwordx4 -> 64 regs, static indices), phi 4x dwordx4 per item,
// neg indices pre-read by lanes 0..3 and shuffled. VMEM/4-items: 21 vs 36 ->
// issue floor ~8.3us (round-17 confirmed aug is VMEM-issue bound).
__global__ __launch_bounds__(256, 3) void aug_dots_kernel(
        const unsigned char* __restrict__ e2f8,
        const unsigned char* __restrict__ phif8,
        const int* __restrict__ neg_idx, float* __restrict__ sexp) {
    int gid = blockIdx.x * 32 + (threadIdx.x >> 3);   // quad-group id
    int sub = threadIdx.x & 7;
    int j = gid / NQUAD;
    int quad = gid - j * NQUAD;
    int ibase = quad * 4;

    // lanes 0..3 pre-read the quad's neg indices (item 0 / item>100 -> j)
    int pre = j;
    {
        int it = ibase + sub;
        if (sub < 4 && it >= 1 && it <= N_NEGS)
            pre = neg_idx[(size_t)j * N_NEGS + it - 1];
    }

    const unsigned char* e = e2f8 + (size_t)j * D_N + sub * 16;
    uint4 ev[4];
    #pragma unroll
    for (int k = 0; k < 4; ++k) ev[k] = *(const uint4*)(e + k * 128);
    float ebx[16], eby[16], ebz[16], ebw[16];
    #pragma unroll
    for (int k = 0; k < 4; ++k) {
        uint ew[4] = {ev[k].x, ev[k].y, ev[k].z, ev[k].w};
        #pragma unroll
        for (int w = 0; w < 4; ++w) {
            f32x2 b0 = __builtin_amdgcn_cvt_pk_f32_fp8((int)ew[w], false);
            f32x2 b1 = __builtin_amdgcn_cvt_pk_f32_fp8((int)ew[w], true);
            ebx[k * 4 + w] = b0.x; eby[k * 4 + w] = b0.y;
            ebz[k * 4 + w] = b1.x; ebw[k * 4 + w] = b1.y;
        }
    }
    #pragma unroll
    for (int q = 0; q < 4; ++q) {
        int item = ibase + q;
        int tgt = __shfl(pre, q, 8);
        const unsigned char* p = phif8 + (size_t)tgt * D_N + sub * 16;
        uint4 pv[4];
        #pragma unroll
        for (int k = 0; k < 4; ++k) pv[k] = *(const uint4*)(p + k * 128);
        float s0 = 0.f, s1 = 0.f;
        #pragma unroll
        for (int k = 0; k < 4; ++k) {
            uint pw[4] = {pv[k].x, pv[k].y, pv[k].z, pv[k].w};
            #pragma unroll
            for (int w = 0; w < 4; ++w) {
                f32x2 a0 = __builtin_amdgcn_cvt_pk_f32_fp8((int)pw[w], false);
                f32x2 a1 = __builtin_amdgcn_cvt_pk_f32_fp8((int)pw[w], true);
                s0 += ebx[k * 4 + w] * a0.x + eby[k * 4 + w] * a0.y;
                s1 += ebz[k * 4 + w] * a1.x + ebw[k * 4 + w] * a1.y;
            }
        }
        float s = s0 + s1;
        s += __shfl_xor(s, 1);
        s += __shfl_xor(s, 2);
        s += __shfl_xor(s, 4);
        if (sub == 0 && item < ITEMS_J)
            sexp[(size_t)j * SEXP_LD + item] = __expf(TAU_F * s);
    }
}

// ---------------------------------------------------------------------------
// final1: 64 blocks; per j: reduce sexp row -> L_a, reduce 32 den/nom
// partial slots -> L_s; write per-block {La,Ls} partials (plain stores).
__global__ __launch_bounds__(256) void final1_kernel(
        const float* __restrict__ sexp, const float* __restrict__ pden,
        const float* __restrict__ pnom, const int* __restrict__ tag,
        float* __restrict__ stat) {
    __shared__ float wla[4], wls[4];
    int lane = threadIdx.x & 63, w = threadIdx.x >> 6;
    int j0 = blockIdx.x * 64;
    float la = 0.f, ls = 0.f;
    for (int jj = w; jj < 64; jj += 4) {
        int j = j0 + jj;
        float v0 = sexp[(size_t)j * SEXP_LD + lane];
        float v1 = (lane + 64 < ITEMS_J) ? sexp[(size_t)j * SEXP_LD + lane + 64] : 0.f;
        float pos = __shfl(v0, 0);
        float ns = ((lane >= 1) ? v0 : 0.f) + v1;
        float d = (lane < 32) ? pden[lane * B_N + j] : 0.f;
        float n = (lane < 32) ? pnom[lane * B_N + j] : 0.f;
        #pragma unroll
        for (int mm = 32; mm; mm >>= 1) {
            ns += __shfl_xor(ns, mm);
            d  += __shfl_xor(d, mm);
            n  += __shfl_xor(n, mm);
        }
        if (lane == 0) {
            float La = logf(pos / (EPS_F + pos + ns));
            if (La == La) la += La;
            float Ls = logf(n / (d + EPS_F));
            bool valid = (stat[S_HIST + tag[j]] < (float)B_N) && (Ls == Ls);
            if (valid) ls += Ls;
        }
    }
    if (lane == 0) { wla[w] = la; wls[w] = ls; }
    __syncthreads();
    if (threadIdx.x == 0) {
        stat[S_FIN + blockIdx.x * 2]     = wla[0] + wla[1] + wla[2] + wla[3];
        stat[S_FIN + blockIdx.x * 2 + 1] = wls[0] + wls[1] + wls[2] + wls[3];
    }
}

// ---------------------------------------------------------------------------
__global__ __launch_bounds__(256) void final2_kernel(
        const float* __restrict__ stat, float* __restrict__ out) {
    __shared__ float sred[4];
    int t = threadIdx.x;
    float w2 = block_sum256(t < 64 ? stat[S_W2P + t] : 0.f, sred);
    float la = block_sum256(t < 64 ? stat[S_FIN + 2 * t] : 0.f, sred);
    float ls = block_sum256(t < 64 ? stat[S_FIN + 2 * t + 1] : 0.f, sred);
    if (t == 0) {
        out[0] = stat[S_MSE] / (float)B_N;
        out[1] = REGW_F * (sqrtf(w2) + sqrtf(stat[S_B2]) +
                           sqrtf(stat[S_WH2]) + sqrtf(stat[S_BH2]));
        out[2] = -la / (float)B_N;
        out[3] = -ls / (float)B_N;
    }
}

// ---------------------------------------------------------------------------
extern "C" void kernel_launch(void* const* d_in, const int* in_sizes, int n_in,
                              void* d_out, int out_size, void* d_ws, size_t ws_size,
                              hipStream_t stream) {
    const float* e1       = (const float*)d_in[0];
    const float* e2       = (const float*)d_in[1];
    const float* y_pred   = (const float*)d_in[2];
    const float* y_target = (const float*)d_in[3];
    const float* W_e2     = (const float*)d_in[4];
    const float* b_e2     = (const float*)d_in[5];
    const float* W_head   = (const float*)d_in[6];
    const float* b_head   = (const float*)d_in[7];
    const float* lmbda    = (const float*)d_in[8];
    const int*   mix_idx  = (const int*)d_in[9];
    const int*   neg_idx  = (const int*)d_in[10];
    const int*   dtag     = (const int*)d_in[11];
    char* base = (char*)d_ws;
    float* out = (float*)d_out;
    unsigned char* phif8 = (unsigned char*)(base + PHIF8_B);
    unsigned char* e2f8  = (unsigned char*)(base + E2F8_B);
    ushort* wtb  = (ushort*)(base + WTB_B);
    ushort* augb = (ushort*)(base + AUGB_B);
    float*  sexp = (float*)(base + SEXP_B);
    float*  pden = (float*)(base + PDEN_B);
    float*  pnom = (float*)(base + PNOM_B);
    float*  stat = (float*)(base + STAT_B);

    prep_kernel<<<dim3(2115), dim3(256), 0, stream>>>(
        y_pred, y_target, W_e2, b_e2, W_head, b_head, e2, e1, lmbda, mix_idx,
        dtag, wtb, augb, e2f8, stat);
    gemm_kernel<<<dim3(SUPP_NB + 256), dim3(256), 0, stream>>>(
        e2f8, dtag, augb, wtb, b_e2, pden, pnom, phif8);
    aug_dots_kernel<<<dim3(B_N * NQUAD / 32), dim3(256), 0, stream>>>(
        e2f8, phif8, neg_idx, sexp);
    final1_kernel<<<dim3(64), dim3(256), 0, stream>>>(
        sexp, pden, pnom, dtag, stat);
    final2_kernel<<<dim3(1), dim3(256), 0, stream>>>(stat, out);
}